// Round 4
// baseline (310.944 us; speedup 1.0000x reference)
//
#include <hip/hip_runtime.h>

typedef _Float16 f16x8 __attribute__((ext_vector_type(8)));
typedef _Float16 f16x4 __attribute__((ext_vector_type(4)));
typedef __fp16 h16x2 __attribute__((ext_vector_type(2)));
typedef float f32x4 __attribute__((ext_vector_type(4)));
typedef float f32x16 __attribute__((ext_vector_type(16)));

#define BN_EPS 1e-5f
#define SQRT32 5.656854249492381f
#define LOG2E  1.4426950408889634f

typedef const __attribute__((address_space(1))) void* gas_p;
typedef __attribute__((address_space(3))) void* las_p;

// ---------------------------------------------------------------- prep (merged)
// z<16: x [b][c=384][n] fp32 -> xT_hi/lo [b][n][c] fp16 planes (transpose+split).
// z==16: weight conversion + BN affine fold.
__global__ __launch_bounds__(256) void prep(
    const float* __restrict__ x,
    const float* __restrict__ wq, const float* __restrict__ wk,
    const float* __restrict__ wv, const float* __restrict__ wp,
    const float* __restrict__ bnq, const float* __restrict__ bnk,
    const float* __restrict__ bnv, const float* __restrict__ bnp,
    _Float16* __restrict__ xT_hi, _Float16* __restrict__ xT_lo,
    _Float16* __restrict__ wqk_h, _Float16* __restrict__ wqk_l,
    _Float16* __restrict__ wv_h,  _Float16* __restrict__ wp_h,
    float* __restrict__ s_qkv, float* __restrict__ t_qkv,
    float* __restrict__ s_p,   float* __restrict__ t_p)
{
    __shared__ float Tx[64][65];
    const int t = threadIdx.x;
    if (blockIdx.z < 16) {
        const int ct = blockIdx.x, nt = blockIdx.y, b = blockIdx.z;
        const int c0 = ct * 64, n0 = nt * 64;
        {
            int tr = t >> 4, tc = (t & 15) * 4;
            #pragma unroll
            for (int p = 0; p < 4; p++) {
                int r = tr + p * 16;
                float4 v = *(const float4*)(x + ((size_t)(b * 384 + c0 + r)) * 1024 + n0 + tc);
                Tx[r][tc + 0] = v.x; Tx[r][tc + 1] = v.y; Tx[r][tc + 2] = v.z; Tx[r][tc + 3] = v.w;
            }
        }
        __syncthreads();
        {
            int nn = t >> 2, cc = (t & 3) * 16;
            f16x8 h0, h1, l0, l1;
            #pragma unroll
            for (int i = 0; i < 8; i++) {
                float v = Tx[cc + i][nn];
                _Float16 hh = (_Float16)v;
                h0[i] = hh; l0[i] = (_Float16)(v - (float)hh);
            }
            #pragma unroll
            for (int i = 0; i < 8; i++) {
                float v = Tx[cc + 8 + i][nn];
                _Float16 hh = (_Float16)v;
                h1[i] = hh; l1[i] = (_Float16)(v - (float)hh);
            }
            size_t o = ((size_t)(b * 1024 + n0 + nn)) * 384 + c0 + cc;
            *(f16x8*)(xT_hi + o) = h0; *(f16x8*)(xT_hi + o + 8) = h1;
            *(f16x8*)(xT_lo + o) = l0; *(f16x8*)(xT_lo + o + 8) = l1;
        }
    } else {
        const int NQK = 512 * 384, NV = 1024 * 384, NP = 384 * 1024;
        int tid = (blockIdx.y * 6 + blockIdx.x) * 256 + t;       // 0..24575
        for (int i = tid; i < NQK + NV + NP; i += 24576) {
            if (i < NQK) {
                int o = i / 384, c = i - o * 384;
                float v = (o < 256) ? wq[o * 384 + c] : wk[(o - 256) * 384 + c];
                _Float16 hh = (_Float16)v;
                wqk_h[i] = hh; wqk_l[i] = (_Float16)(v - (float)hh);
            } else if (i < NQK + NV) {
                wv_h[i - NQK] = (_Float16)wv[i - NQK];
            } else {
                wp_h[i - NQK - NV] = (_Float16)wp[i - NQK - NV];
            }
        }
        if (tid < 1536) {
            int i = tid;
            float g, be, m, v;
            if (i < 256)      { int o = i;       g = bnq[o]; be = bnq[256 + o];  m = bnq[512 + o];  v = bnq[768 + o]; }
            else if (i < 512) { int o = i - 256; g = bnk[o]; be = bnk[256 + o];  m = bnk[512 + o];  v = bnk[768 + o]; }
            else              { int o = i - 512; g = bnv[o]; be = bnv[1024 + o]; m = bnv[2048 + o]; v = bnv[3072 + o]; }
            float s = g * rsqrtf(v + BN_EPS);
            float tt = be - m * s;
            // fold /scale (= *sqrt(kd)) AND log2(e) (exp2 softmax) into Q's affine
            if (i < 256) { s *= SQRT32 * LOG2E; tt *= SQRT32 * LOG2E; }
            s_qkv[i] = s; t_qkv[i] = tt;
        } else if (tid < 1536 + 384) {
            int o = tid - 1536;
            float g = bnp[o], be = bnp[384 + o], m = bnp[768 + o], v = bnp[1152 + o];
            float s = g * rsqrtf(v + BN_EPS);
            s_p[o] = s; t_p[o] = be - m * s;
        }
    }
}

// ---------------------------------------------------------------- gemm_qkv
// bx<4 (Q/K rows): computes D[n][o] (transposed, 3-term hi/lo) and writes
// qT [b][h][n][32] planes; kT in frag-linear layout
// [bh][kt(16)][frag(4)=(sub,kh)][lane(64)=(hl,L)][8] so attn's K DMA is a
// straight contiguous 4KB copy.
// bx>=4 (V rows): D[o][n] 1-term, fp16 out; vbuf stores each 64-key tile in
// PV-fragment order (8B chunks permuted [0,2,1,3] within 32B groups) so
// attn's PV A-frag is a single ds_read_b128.
__global__ __launch_bounds__(256, 2) void gemm_qkv(
    const _Float16* __restrict__ wqk_h, const _Float16* __restrict__ wqk_l,
    const _Float16* __restrict__ wv_h,
    const _Float16* __restrict__ xT_hi, const _Float16* __restrict__ xT_lo,
    const float* __restrict__ S, const float* __restrict__ T,
    _Float16* __restrict__ qT_h, _Float16* __restrict__ qT_l,
    _Float16* __restrict__ kT_h, _Float16* __restrict__ kT_l,
    _Float16* __restrict__ vbuf)
{
    __shared__ __align__(16) _Float16 As_h[128 * 40];
    __shared__ __align__(16) _Float16 As_l[128 * 40];
    __shared__ __align__(16) _Float16 Bs_h[128 * 40];
    __shared__ __align__(16) _Float16 Bs_l[128 * 40];
    const int t = threadIdx.x, lane = t & 63, w = t >> 6;
    const int wr = w >> 1, wc = w & 1, l16 = lane & 15, lq = lane >> 4;
    const int bx = blockIdx.x, n0 = blockIdx.y * 128, b = blockIdx.z;
    const bool isv = bx >= 4;
    const int o0 = isv ? (bx - 4) * 128 : bx * 128;
    const _Float16* __restrict__ Ah = isv ? wv_h : wqk_h;

    f32x4 acc[4][4] = {};

    for (int kb = 0; kb < 384; kb += 32) {
        __syncthreads();
        #pragma unroll
        for (int p = 0; p < 2; p++) {
            int g = t + p * 256, row = g >> 2, ch = g & 3;
            *(uint4*)(&As_h[row * 40 + ch * 8]) =
                *(const uint4*)(Ah + (size_t)(o0 + row) * 384 + kb + ch * 8);
        }
        #pragma unroll
        for (int p = 0; p < 2; p++) {
            int g = t + p * 256, row = g >> 2, ch = g & 3;
            *(uint4*)(&Bs_h[row * 40 + ch * 8]) =
                *(const uint4*)(xT_hi + ((size_t)(b * 1024) + n0 + row) * 384 + kb + ch * 8);
        }
        if (!isv) {
            #pragma unroll
            for (int p = 0; p < 2; p++) {
                int g = t + p * 256, row = g >> 2, ch = g & 3;
                *(uint4*)(&As_l[row * 40 + ch * 8]) =
                    *(const uint4*)(wqk_l + (size_t)(o0 + row) * 384 + kb + ch * 8);
            }
            #pragma unroll
            for (int p = 0; p < 2; p++) {
                int g = t + p * 256, row = g >> 2, ch = g & 3;
                *(uint4*)(&Bs_l[row * 40 + ch * 8]) =
                    *(const uint4*)(xT_lo + ((size_t)(b * 1024) + n0 + row) * 384 + kb + ch * 8);
            }
        }
        __syncthreads();

        if (!isv) {
            // transposed: A = x tiles (n rows), B = w tiles (o cols)
            f16x8 ah[4], al[4], bh[4], bl[4];
            #pragma unroll
            for (int i = 0; i < 4; i++) {
                ah[i] = *(const f16x8*)(&Bs_h[(wr * 64 + i * 16 + l16) * 40 + lq * 8]);
                al[i] = *(const f16x8*)(&Bs_l[(wr * 64 + i * 16 + l16) * 40 + lq * 8]);
            }
            #pragma unroll
            for (int j = 0; j < 4; j++) {
                bh[j] = *(const f16x8*)(&As_h[(wc * 64 + j * 16 + l16) * 40 + lq * 8]);
                bl[j] = *(const f16x8*)(&As_l[(wc * 64 + j * 16 + l16) * 40 + lq * 8]);
            }
            #pragma unroll
            for (int i = 0; i < 4; i++)
                #pragma unroll
                for (int j = 0; j < 4; j++) {
                    acc[i][j] = __builtin_amdgcn_mfma_f32_16x16x32_f16(ah[i], bh[j], acc[i][j], 0, 0, 0);
                    acc[i][j] = __builtin_amdgcn_mfma_f32_16x16x32_f16(al[i], bh[j], acc[i][j], 0, 0, 0);
                    acc[i][j] = __builtin_amdgcn_mfma_f32_16x16x32_f16(ah[i], bl[j], acc[i][j], 0, 0, 0);
                }
        } else {
            f16x8 a[4], bf[4];
            #pragma unroll
            for (int i = 0; i < 4; i++) a[i]  = *(const f16x8*)(&As_h[(wr * 64 + i * 16 + l16) * 40 + lq * 8]);
            #pragma unroll
            for (int j = 0; j < 4; j++) bf[j] = *(const f16x8*)(&Bs_h[(wc * 64 + j * 16 + l16) * 40 + lq * 8]);
            #pragma unroll
            for (int i = 0; i < 4; i++)
                #pragma unroll
                for (int j = 0; j < 4; j++)
                    acc[i][j] = __builtin_amdgcn_mfma_f32_16x16x32_f16(a[i], bf[j], acc[i][j], 0, 0, 0);
        }
    }

    if (!isv) {
        // D[n][o]: row = n, col(l16) = o.
        #pragma unroll
        for (int i = 0; i < 4; i++) {
            #pragma unroll
            for (int r = 0; r < 4; r++) {
                int n = n0 + wr * 64 + i * 16 + lq * 4 + r;
                #pragma unroll
                for (int j = 0; j < 4; j++) {
                    int o = o0 + wc * 64 + j * 16 + l16;
                    float sc = S[o], sh = T[o];
                    float v = acc[i][j][r] * sc + sh;
                    _Float16 hh = (_Float16)v;
                    _Float16 ll = (_Float16)(v - (float)hh);
                    if (o < 256) {
                        size_t idx = (((size_t)(b * 8) + (o >> 5)) * 1024 + n) * 32 + (o & 31);
                        qT_h[idx] = hh; qT_l[idx] = ll;
                    } else {
                        int oo = o - 256;
                        int hd = oo >> 5, c = oo & 31;
                        int f = ((n >> 5) & 1) * 2 + (c >> 4);           // (sub, kh)
                        size_t idx = ((((size_t)(b * 8 + hd) * 16 + (n >> 6)) * 4 + f) * 64
                                      + ((c >> 3) & 1) * 32 + (n & 31)) * 8 + (c & 7);
                        kT_h[idx] = hh; kT_l[idx] = ll;
                    }
                }
            }
        }
    } else {
        #pragma unroll
        for (int i = 0; i < 4; i++) {
            #pragma unroll
            for (int r = 0; r < 4; r++) {
                int o = o0 + wr * 64 + i * 16 + lq * 4 + r;
                float sc = S[512 + o], sh = T[512 + o];
                #pragma unroll
                for (int j = 0; j < 4; j++) {
                    int n = n0 + wc * 64 + j * 16 + l16;
                    // PV-fragment order within each 64-key tile:
                    // chunk c4=(k>>2)&3 goes to slot {0,2,1,3}[c4]
                    int k = n & 63;
                    int s4 = k >> 4, c4 = (k >> 2) & 3;
                    int ep = s4 * 16 + (c4 & 1) * 8 + (c4 >> 1) * 4 + (k & 3);
                    int nst = (n & ~63) | ep;
                    vbuf[((size_t)(b * 1024) + o) * 1024 + nst] = (_Float16)(acc[i][j][r] * sc + sh);
                }
            }
        }
    }
}

// ---------------------------------------------------------------- attn
// Online-softmax flash attention. 256 thr = 4 waves, 128 q/block,
// grid (bh=128, qt=8) = 1024 blocks.
// REGISTER DIET for 3 waves/SIMD (combined VGPR+AGPR <= 168): each 64-key
// tile is processed as two sequential 32-key halves, so only ONE f32x16 QK
// accumulator is ever live (AGPR peak 80 = o_acc 64 + c 16, vs 96 before).
// sched_barrier(0) at the half boundary stops the compiler re-merging them.
// K tile: frag-linear in LDS via global_load_lds (ds_read_b128 conflict-free).
// V tile: PV-fragment-ordered + XOR swizzle; PV A-frag = single ds_read_b128.
// Defer-max (THR=8) gates the o_acc rescale; exp2 via Q-folded log2(e).
__device__ __forceinline__ f32x16 qk6(f16x8 kh0, f16x8 kl0, f16x8 kh1, f16x8 kl1,
                                      f16x8 qh0, f16x8 ql0, f16x8 qh1, f16x8 ql1) {
    f32x16 c = {};
    c = __builtin_amdgcn_mfma_f32_32x32x16_f16(kh0, qh0, c, 0, 0, 0);
    c = __builtin_amdgcn_mfma_f32_32x32x16_f16(kl0, qh0, c, 0, 0, 0);
    c = __builtin_amdgcn_mfma_f32_32x32x16_f16(kh0, ql0, c, 0, 0, 0);
    c = __builtin_amdgcn_mfma_f32_32x32x16_f16(kh1, qh1, c, 0, 0, 0);
    c = __builtin_amdgcn_mfma_f32_32x32x16_f16(kl1, qh1, c, 0, 0, 0);
    c = __builtin_amdgcn_mfma_f32_32x32x16_f16(kh1, ql1, c, 0, 0, 0);
    return c;
}

__global__ __launch_bounds__(256, 3) void attn(
    const _Float16* __restrict__ qT_h, const _Float16* __restrict__ qT_l,
    const _Float16* __restrict__ kT_h, const _Float16* __restrict__ kT_l,
    const _Float16* __restrict__ vbuf,
    _Float16* __restrict__ xxT_h, _Float16* __restrict__ xxT_l)
{
    __shared__ __align__(16) _Float16 Vs[2][128 * 64];
    __shared__ __align__(16) _Float16 Ksh[2][2048];
    __shared__ __align__(16) _Float16 Ksl[2][2048];
    const int t = threadIdx.x, lane = t & 63, w = t >> 6;
    const int L = lane & 31, hl = lane >> 5;
    const int bh = blockIdx.x, qt = blockIdx.y;
    const int b = bh >> 3, h = bh & 7;
    const size_t vbase = ((size_t)(b * 1024) + h * 128) * 1024;

    // Q B-frags (hi/lo planes); once per block
    f16x8 bq_h[2], bq_l[2];
    {
        int q = qt * 128 + w * 32 + L;
        #pragma unroll
        for (int kh = 0; kh < 2; kh++) {
            size_t base = ((size_t)(bh * 1024) + q) * 32 + kh * 16 + hl * 8;
            bq_h[kh] = *(const f16x8*)(qT_h + base);
            bq_l[kh] = *(const f16x8*)(qT_l + base);
        }
    }

    f32x16 o_acc[4] = {};
    float m_st = -INFINITY, l_st = 0.f;

    // async DMA of K (frag-linear, 4KB/plane) + V tile into buf.
    #define DMA_TILE(buf, kt_)                                                     \
        {                                                                          \
            size_t ktb = (size_t)(bh * 16 + (kt_)) * 2048 + (size_t)t * 8;         \
            __builtin_amdgcn_global_load_lds((gas_p)(const void*)(kT_h + ktb),     \
                                             (las_p)(void*)&Ksh[buf][w * 512], 16, 0, 0); \
            __builtin_amdgcn_global_load_lds((gas_p)(const void*)(kT_l + ktb),     \
                                             (las_p)(void*)&Ksl[buf][w * 512], 16, 0, 0); \
            _Pragma("unroll")                                                      \
            for (int p = 0; p < 4; p++) {                                          \
                int g2 = t + p * 256;                                              \
                int d = g2 >> 3;                                                   \
                int kcg = (g2 & 7) ^ (d & 7);                                      \
                const _Float16* src = vbuf + vbase + (size_t)d * 1024              \
                                      + (kt_) * 64 + kcg * 8;                      \
                _Float16* dst = &Vs[buf][(p * 256 + w * 64) * 8];                  \
                __builtin_amdgcn_global_load_lds((gas_p)(const void*)src,          \
                                                 (las_p)(void*)dst, 16, 0, 0);     \
            }                                                                      \
        }

    DMA_TILE(0, 0)
    __syncthreads();

    for (int kt = 0; kt < 16; kt++) {
        const int cur = kt & 1;

        if (kt < 15) DMA_TILE(cur ^ 1, kt + 1)

        #pragma unroll
        for (int hv = 0; hv < 2; hv++) {
            // K frags for this 32-key half (lgkmcnt only; DMA stays in flight)
            const _Float16* khp = &Ksh[cur][hv * 1024 + lane * 8];
            const _Float16* klp = &Ksl[cur][hv * 1024 + lane * 8];
            f16x8 K0h = *(const f16x8*)(khp);
            f16x8 K1h = *(const f16x8*)(khp + 512);
            f16x8 K0l = *(const f16x8*)(klp);
            f16x8 K1l = *(const f16x8*)(klp + 512);

            __builtin_amdgcn_s_setprio(1);
            f32x16 c = qk6(K0h, K0l, K1h, K1l, bq_h[0], bq_l[0], bq_h[1], bq_l[1]);
            __builtin_amdgcn_s_setprio(0);

            // tree row-max (depth 4)
            float tmx[8];
            #pragma unroll
            for (int i = 0; i < 8; i++) tmx[i] = fmaxf(c[i], c[i + 8]);
            #pragma unroll
            for (int st = 4; st >= 1; st >>= 1)
                #pragma unroll
                for (int i = 0; i < st; i++) tmx[i] = fmaxf(tmx[i], tmx[i + st]);
            float mx = fmaxf(tmx[0], __shfl_xor(tmx[0], 32, 64));

            // defer-max: only rescale when the row max grows by > 8
            if (__any(mx > m_st + 8.f)) {
                float mnew = fmaxf(m_st, mx);
                float a = exp2f(m_st - mnew);
                l_st *= a;
                #pragma unroll
                for (int dt = 0; dt < 4; dt++)
                    #pragma unroll
                    for (int i = 0; i < 16; i++) o_acc[dt][i] *= a;
                m_st = mnew;
            }

            // exp -> packed f16 (cvt_pkrtz), partial-sum tree
            f16x8 pf[2];
            float rs = 0.f;
            #pragma unroll
            for (int s = 0; s < 2; s++) {
                float pv[8];
                #pragma unroll
                for (int j = 0; j < 8; j++)
                    pv[j] = exp2f(c[s * 8 + j] - m_st);
                rs += ((pv[0] + pv[1]) + (pv[2] + pv[3])) + ((pv[4] + pv[5]) + (pv[6] + pv[7]));
                union { f16x8 v; h16x2 hh[4]; } u;
                #pragma unroll
                for (int j = 0; j < 4; j++)
                    u.hh[j] = __builtin_amdgcn_cvt_pkrtz(pv[2 * j], pv[2 * j + 1]);
                pf[s] = u.v;
            }
            l_st += rs;

            // O[d][q] += V * P for this half's 2 slots (single ds_read_b128 A-frag)
            __builtin_amdgcn_s_setprio(1);
            #pragma unroll
            for (int s2 = 0; s2 < 2; s2++) {
                int s = hv * 2 + s2;
                int cp = (2 * s + hl) ^ (L & 7);
                #pragma unroll
                for (int dt = 0; dt < 4; dt++) {
                    f16x8 avp = *(const f16x8*)(&Vs[cur][(dt * 32 + L) * 64 + cp * 8]);
                    o_acc[dt] = __builtin_amdgcn_mfma_f32_32x32x16_f16(avp, pf[s2], o_acc[dt], 0, 0, 0);
                }
            }
            __builtin_amdgcn_s_setprio(0);

            // keep the two halves strictly sequential so only one QK
            // accumulator is ever live (register budget for 3 waves/SIMD)
            __builtin_amdgcn_sched_barrier(0);
        }

        if (kt < 15) __syncthreads();   // drains this iter's DMA + joins waves
    }
    #undef DMA_TILE

    l_st += __shfl_xor(l_st, 32, 64);

    // epilogue: normalize, split hi/lo, store xxT[b][n=q][d]
    {
        float rl = 1.f / l_st;
        int q = qt * 128 + w * 32 + L;
        #pragma unroll
        for (int dt = 0; dt < 4; dt++) {
            #pragma unroll
            for (int gg = 0; gg < 4; gg++) {
                f16x4 hv, lv;
                #pragma unroll
                for (int rr = 0; rr < 4; rr++) {
                    float v = o_acc[dt][gg * 4 + rr] * rl;
                    _Float16 hh = (_Float16)v;
                    hv[rr] = hh; lv[rr] = (_Float16)(v - (float)hh);
                }
                size_t o = ((size_t)(b * 1024) + q) * 1024 + h * 128 + dt * 32 + gg * 8 + hl * 4;
                *(f16x4*)(xxT_h + o) = hv;
                *(f16x4*)(xxT_l + o) = lv;
            }
        }
    }
}

// ---------------------------------------------------------------- gemm_out
// out[o][n] = (sum_c Wp[o,c]*xx[c,n]) * s + t, 2-term hi/lo on xx. fp32 out.
__global__ __launch_bounds__(256, 2) void gemm_out(
    const _Float16* __restrict__ wp_h,
    const _Float16* __restrict__ xxT_h, const _Float16* __restrict__ xxT_l,
    const float* __restrict__ S, const float* __restrict__ T,
    float* __restrict__ out)
{
    __shared__ __align__(16) _Float16 As[128 * 40];
    __shared__ __align__(16) _Float16 Bh[64 * 40];
    __shared__ __align__(16) _Float16 Bl[64 * 40];
    const int t = threadIdx.x, lane = t & 63, w = t >> 6;
    const int wr = w >> 1, wc = w & 1, l16 = lane & 15, lq = lane >> 4;
    const int o0 = blockIdx.x * 128, n0 = blockIdx.y * 64, b = blockIdx.z;

    f32x4 acc[4][2] = {};

    for (int kb = 0; kb < 1024; kb += 32) {
        __syncthreads();
        #pragma unroll
        for (int p = 0; p < 2; p++) {
            int g = t + p * 256, row = g >> 2, ch = g & 3;
            *(uint4*)(&As[row * 40 + ch * 8]) =
                *(const uint4*)(wp_h + (size_t)(o0 + row) * 1024 + kb + ch * 8);
        }
        {
            int row = t >> 2, ch = t & 3;
            size_t src = ((size_t)(b * 1024) + n0 + row) * 1024 + kb + ch * 8;
            *(uint4*)(&Bh[row * 40 + ch * 8]) = *(const uint4*)(xxT_h + src);
            *(uint4*)(&Bl[row * 40 + ch * 8]) = *(const uint4*)(xxT_l + src);
        }
        __syncthreads();

        f16x8 a[4], bh[2], bl[2];
        #pragma unroll
        for (int i = 0; i < 4; i++) a[i] = *(const f16x8*)(&As[(wr * 64 + i * 16 + l16) * 40 + lq * 8]);
        #pragma unroll
        for (int j = 0; j < 2; j++) {
            bh[j] = *(const f16x8*)(&Bh[(wc * 32 + j * 16 + l16) * 40 + lq * 8]);
            bl[j] = *(const f16x8*)(&Bl[(wc * 32 + j * 16 + l16) * 40 + lq * 8]);
        }
        #pragma unroll
        for (int i = 0; i < 4; i++)
            #pragma unroll
            for (int j = 0; j < 2; j++) {
                acc[i][j] = __builtin_amdgcn_mfma_f32_16x16x32_f16(a[i], bh[j], acc[i][j], 0, 0, 0);
                acc[i][j] = __builtin_amdgcn_mfma_f32_16x16x32_f16(a[i], bl[j], acc[i][j], 0, 0, 0);
            }
    }

    #pragma unroll
    for (int i = 0; i < 4; i++) {
        #pragma unroll
        for (int r = 0; r < 4; r++) {
            int o = o0 + wr * 64 + i * 16 + lq * 4 + r;
            float sc = S[o], sh = T[o];
            #pragma unroll
            for (int j = 0; j < 2; j++) {
                int n = n0 + wc * 32 + j * 16 + l16;
                out[((size_t)(b * 384) + o) * 1024 + n] = acc[i][j][r] * sc + sh;
            }
        }
    }
}

// ---------------------------------------------------------------- launch

extern "C" void kernel_launch(void* const* d_in, const int* in_sizes, int n_in,
                              void* d_out, int out_size, void* d_ws, size_t ws_size,
                              hipStream_t stream) {
    const float* x   = (const float*)d_in[0];
    const float* wq  = (const float*)d_in[1];
    const float* bnq = (const float*)d_in[2];
    const float* wk  = (const float*)d_in[3];
    const float* bnk = (const float*)d_in[4];
    const float* wv  = (const float*)d_in[5];
    const float* bnv = (const float*)d_in[6];
    const float* wp  = (const float*)d_in[7];
    const float* bnp = (const float*)d_in[8];
    float* out = (float*)d_out;
    (void)in_sizes; (void)n_in; (void)out_size; (void)ws_size;

    char* ws = (char*)d_ws;
    size_t off = 0;
    auto alloc = [&](size_t bytes) {
        void* p = ws + off;
        off = (off + bytes + 255) & ~(size_t)255;
        return p;
    };
    // --- region A: dead after gemm_qkv; reused as xxT_h (needs >= 33.56 MB) ---
    _Float16* xT_hi = (_Float16*)alloc((size_t)16 * 1024 * 384 * 2);   // 12.58 MB
    _Float16* xT_lo = (_Float16*)alloc((size_t)16 * 1024 * 384 * 2);   // 12.58 MB
    _Float16* wqk_h = (_Float16*)alloc((size_t)512 * 384 * 2);
    _Float16* wqk_l = (_Float16*)alloc((size_t)512 * 384 * 2);
    _Float16* wv_h  = (_Float16*)alloc((size_t)1024 * 384 * 2);
    alloc((size_t)7 * 1024 * 1024);                                     // pad region A to > 33.56 MB
    _Float16* xxT_h = (_Float16*)d_ws;                                  // alias over region A
    // --- live buffers ---
    _Float16* wp_h  = (_Float16*)alloc((size_t)384 * 1024 * 2);
    float*    s_qkv = (float*)alloc(1536 * 4);
    float*    t_qkv = (float*)alloc(1536 * 4);
    float*    s_p   = (float*)alloc(384 * 4);
    float*    t_p   = (float*)alloc(384 * 4);
    _Float16* qT_h  = (_Float16*)alloc((size_t)16 * 8 * 1024 * 32 * 2); // 8.39 MB
    _Float16* qT_l  = (_Float16*)alloc((size_t)16 * 8 * 1024 * 32 * 2); // 8.39 MB
    _Float16* kT_h  = (_Float16*)alloc((size_t)16 * 8 * 1024 * 32 * 2); // 8.39 MB
    _Float16* kT_l  = (_Float16*)alloc((size_t)16 * 8 * 1024 * 32 * 2); // 8.39 MB
    _Float16* vbuf  = (_Float16*)alloc((size_t)16 * 1024 * 1024 * 2);   // 33.55 MB
    _Float16* xxT_l = (_Float16*)alloc((size_t)16 * 1024 * 1024 * 2);   // 33.55 MB

    prep<<<dim3(6, 16, 17), dim3(256), 0, stream>>>(
        x, wq, wk, wv, wp, bnq, bnk, bnv, bnp,
        xT_hi, xT_lo, wqk_h, wqk_l, wv_h, wp_h, s_qkv, t_qkv, s_p, t_p);

    gemm_qkv<<<dim3(12, 8, 16), dim3(256), 0, stream>>>(
        wqk_h, wqk_l, wv_h, xT_hi, xT_lo, s_qkv, t_qkv,
        qT_h, qT_l, kT_h, kT_l, vbuf);

    attn<<<dim3(128, 8), dim3(256), 0, stream>>>(qT_h, qT_l, kT_h, kT_l, vbuf, xxT_h, xxT_l);

    gemm_out<<<dim3(3, 16, 16), dim3(256), 0, stream>>>(wp_h, xxT_h, xxT_l, s_p, t_p, out);
}

// Round 6
// 307.245 us; speedup vs baseline: 1.0120x; 1.0120x over previous
//
#include <hip/hip_runtime.h>

typedef _Float16 f16x8 __attribute__((ext_vector_type(8)));
typedef _Float16 f16x4 __attribute__((ext_vector_type(4)));
typedef __fp16 h16x2 __attribute__((ext_vector_type(2)));
typedef float f32x4 __attribute__((ext_vector_type(4)));
typedef float f32x16 __attribute__((ext_vector_type(16)));

#define BN_EPS 1e-5f
#define SQRT32 5.656854249492381f
#define LOG2E  1.4426950408889634f

typedef const __attribute__((address_space(1))) void* gas_p;
typedef __attribute__((address_space(3))) void* las_p;

// ---------------------------------------------------------------- prep (merged)
// z<16: x [b][c=384][n] fp32 -> xT_hi/lo [b][n][c] fp16 planes (transpose+split).
// z==16: weight conversion + BN affine fold.
__global__ __launch_bounds__(256) void prep(
    const float* __restrict__ x,
    const float* __restrict__ wq, const float* __restrict__ wk,
    const float* __restrict__ wv, const float* __restrict__ wp,
    const float* __restrict__ bnq, const float* __restrict__ bnk,
    const float* __restrict__ bnv, const float* __restrict__ bnp,
    _Float16* __restrict__ xT_hi, _Float16* __restrict__ xT_lo,
    _Float16* __restrict__ wqk_h, _Float16* __restrict__ wqk_l,
    _Float16* __restrict__ wv_h,  _Float16* __restrict__ wp_h,
    float* __restrict__ s_qkv, float* __restrict__ t_qkv,
    float* __restrict__ s_p,   float* __restrict__ t_p)
{
    __shared__ float Tx[64][65];
    const int t = threadIdx.x;
    if (blockIdx.z < 16) {
        const int ct = blockIdx.x, nt = blockIdx.y, b = blockIdx.z;
        const int c0 = ct * 64, n0 = nt * 64;
        {
            int tr = t >> 4, tc = (t & 15) * 4;
            #pragma unroll
            for (int p = 0; p < 4; p++) {
                int r = tr + p * 16;
                float4 v = *(const float4*)(x + ((size_t)(b * 384 + c0 + r)) * 1024 + n0 + tc);
                Tx[r][tc + 0] = v.x; Tx[r][tc + 1] = v.y; Tx[r][tc + 2] = v.z; Tx[r][tc + 3] = v.w;
            }
        }
        __syncthreads();
        {
            int nn = t >> 2, cc = (t & 3) * 16;
            f16x8 h0, h1, l0, l1;
            #pragma unroll
            for (int i = 0; i < 8; i++) {
                float v = Tx[cc + i][nn];
                _Float16 hh = (_Float16)v;
                h0[i] = hh; l0[i] = (_Float16)(v - (float)hh);
            }
            #pragma unroll
            for (int i = 0; i < 8; i++) {
                float v = Tx[cc + 8 + i][nn];
                _Float16 hh = (_Float16)v;
                h1[i] = hh; l1[i] = (_Float16)(v - (float)hh);
            }
            size_t o = ((size_t)(b * 1024 + n0 + nn)) * 384 + c0 + cc;
            *(f16x8*)(xT_hi + o) = h0; *(f16x8*)(xT_hi + o + 8) = h1;
            *(f16x8*)(xT_lo + o) = l0; *(f16x8*)(xT_lo + o + 8) = l1;
        }
    } else {
        const int NQK = 512 * 384, NV = 1024 * 384, NP = 384 * 1024;
        int tid = (blockIdx.y * 6 + blockIdx.x) * 256 + t;       // 0..24575
        for (int i = tid; i < NQK + NV + NP; i += 24576) {
            if (i < NQK) {
                int o = i / 384, c = i - o * 384;
                float v = (o < 256) ? wq[o * 384 + c] : wk[(o - 256) * 384 + c];
                _Float16 hh = (_Float16)v;
                wqk_h[i] = hh; wqk_l[i] = (_Float16)(v - (float)hh);
            } else if (i < NQK + NV) {
                wv_h[i - NQK] = (_Float16)wv[i - NQK];
            } else {
                wp_h[i - NQK - NV] = (_Float16)wp[i - NQK - NV];
            }
        }
        if (tid < 1536) {
            int i = tid;
            float g, be, m, v;
            if (i < 256)      { int o = i;       g = bnq[o]; be = bnq[256 + o];  m = bnq[512 + o];  v = bnq[768 + o]; }
            else if (i < 512) { int o = i - 256; g = bnk[o]; be = bnk[256 + o];  m = bnk[512 + o];  v = bnk[768 + o]; }
            else              { int o = i - 512; g = bnv[o]; be = bnv[1024 + o]; m = bnv[2048 + o]; v = bnv[3072 + o]; }
            float s = g * rsqrtf(v + BN_EPS);
            float tt = be - m * s;
            // fold /scale (= *sqrt(kd)) AND log2(e) (exp2 softmax) into Q's affine
            if (i < 256) { s *= SQRT32 * LOG2E; tt *= SQRT32 * LOG2E; }
            s_qkv[i] = s; t_qkv[i] = tt;
        } else if (tid < 1536 + 384) {
            int o = tid - 1536;
            float g = bnp[o], be = bnp[384 + o], m = bnp[768 + o], v = bnp[1152 + o];
            float s = g * rsqrtf(v + BN_EPS);
            s_p[o] = s; t_p[o] = be - m * s;
        }
    }
}

// ---------------------------------------------------------------- gemm_qkv
// bx<4 (Q/K rows): computes D[n][o] (transposed, 3-term hi/lo) and writes
// qT [b][h][n][32] planes; kT in frag-linear layout
// [bh][kt(16)][frag(4)=(sub,kh)][lane(64)=(hl,L)][8] so attn's K DMA is a
// straight contiguous 4KB copy.
// bx>=4 (V rows): D[o][n] 1-term, fp16 out; vbuf stores each 64-key tile in
// PV-fragment order (8B chunks permuted [0,2,1,3] within 32B groups) so
// attn's PV A-frag is a single ds_read_b128.
__global__ __launch_bounds__(256, 2) void gemm_qkv(
    const _Float16* __restrict__ wqk_h, const _Float16* __restrict__ wqk_l,
    const _Float16* __restrict__ wv_h,
    const _Float16* __restrict__ xT_hi, const _Float16* __restrict__ xT_lo,
    const float* __restrict__ S, const float* __restrict__ T,
    _Float16* __restrict__ qT_h, _Float16* __restrict__ qT_l,
    _Float16* __restrict__ kT_h, _Float16* __restrict__ kT_l,
    _Float16* __restrict__ vbuf)
{
    __shared__ __align__(16) _Float16 As_h[128 * 40];
    __shared__ __align__(16) _Float16 As_l[128 * 40];
    __shared__ __align__(16) _Float16 Bs_h[128 * 40];
    __shared__ __align__(16) _Float16 Bs_l[128 * 40];
    const int t = threadIdx.x, lane = t & 63, w = t >> 6;
    const int wr = w >> 1, wc = w & 1, l16 = lane & 15, lq = lane >> 4;
    const int bx = blockIdx.x, n0 = blockIdx.y * 128, b = blockIdx.z;
    const bool isv = bx >= 4;
    const int o0 = isv ? (bx - 4) * 128 : bx * 128;
    const _Float16* __restrict__ Ah = isv ? wv_h : wqk_h;

    f32x4 acc[4][4] = {};

    for (int kb = 0; kb < 384; kb += 32) {
        __syncthreads();
        #pragma unroll
        for (int p = 0; p < 2; p++) {
            int g = t + p * 256, row = g >> 2, ch = g & 3;
            *(uint4*)(&As_h[row * 40 + ch * 8]) =
                *(const uint4*)(Ah + (size_t)(o0 + row) * 384 + kb + ch * 8);
        }
        #pragma unroll
        for (int p = 0; p < 2; p++) {
            int g = t + p * 256, row = g >> 2, ch = g & 3;
            *(uint4*)(&Bs_h[row * 40 + ch * 8]) =
                *(const uint4*)(xT_hi + ((size_t)(b * 1024) + n0 + row) * 384 + kb + ch * 8);
        }
        if (!isv) {
            #pragma unroll
            for (int p = 0; p < 2; p++) {
                int g = t + p * 256, row = g >> 2, ch = g & 3;
                *(uint4*)(&As_l[row * 40 + ch * 8]) =
                    *(const uint4*)(wqk_l + (size_t)(o0 + row) * 384 + kb + ch * 8);
            }
            #pragma unroll
            for (int p = 0; p < 2; p++) {
                int g = t + p * 256, row = g >> 2, ch = g & 3;
                *(uint4*)(&Bs_l[row * 40 + ch * 8]) =
                    *(const uint4*)(xT_lo + ((size_t)(b * 1024) + n0 + row) * 384 + kb + ch * 8);
            }
        }
        __syncthreads();

        if (!isv) {
            // transposed: A = x tiles (n rows), B = w tiles (o cols)
            f16x8 ah[4], al[4], bh[4], bl[4];
            #pragma unroll
            for (int i = 0; i < 4; i++) {
                ah[i] = *(const f16x8*)(&Bs_h[(wr * 64 + i * 16 + l16) * 40 + lq * 8]);
                al[i] = *(const f16x8*)(&Bs_l[(wr * 64 + i * 16 + l16) * 40 + lq * 8]);
            }
            #pragma unroll
            for (int j = 0; j < 4; j++) {
                bh[j] = *(const f16x8*)(&As_h[(wc * 64 + j * 16 + l16) * 40 + lq * 8]);
                bl[j] = *(const f16x8*)(&As_l[(wc * 64 + j * 16 + l16) * 40 + lq * 8]);
            }
            #pragma unroll
            for (int i = 0; i < 4; i++)
                #pragma unroll
                for (int j = 0; j < 4; j++) {
                    acc[i][j] = __builtin_amdgcn_mfma_f32_16x16x32_f16(ah[i], bh[j], acc[i][j], 0, 0, 0);
                    acc[i][j] = __builtin_amdgcn_mfma_f32_16x16x32_f16(al[i], bh[j], acc[i][j], 0, 0, 0);
                    acc[i][j] = __builtin_amdgcn_mfma_f32_16x16x32_f16(ah[i], bl[j], acc[i][j], 0, 0, 0);
                }
        } else {
            f16x8 a[4], bf[4];
            #pragma unroll
            for (int i = 0; i < 4; i++) a[i]  = *(const f16x8*)(&As_h[(wr * 64 + i * 16 + l16) * 40 + lq * 8]);
            #pragma unroll
            for (int j = 0; j < 4; j++) bf[j] = *(const f16x8*)(&Bs_h[(wc * 64 + j * 16 + l16) * 40 + lq * 8]);
            #pragma unroll
            for (int i = 0; i < 4; i++)
                #pragma unroll
                for (int j = 0; j < 4; j++)
                    acc[i][j] = __builtin_amdgcn_mfma_f32_16x16x32_f16(a[i], bf[j], acc[i][j], 0, 0, 0);
        }
    }

    if (!isv) {
        // D[n][o]: row = n, col(l16) = o.
        #pragma unroll
        for (int i = 0; i < 4; i++) {
            #pragma unroll
            for (int r = 0; r < 4; r++) {
                int n = n0 + wr * 64 + i * 16 + lq * 4 + r;
                #pragma unroll
                for (int j = 0; j < 4; j++) {
                    int o = o0 + wc * 64 + j * 16 + l16;
                    float sc = S[o], sh = T[o];
                    float v = acc[i][j][r] * sc + sh;
                    _Float16 hh = (_Float16)v;
                    _Float16 ll = (_Float16)(v - (float)hh);
                    if (o < 256) {
                        size_t idx = (((size_t)(b * 8) + (o >> 5)) * 1024 + n) * 32 + (o & 31);
                        qT_h[idx] = hh; qT_l[idx] = ll;
                    } else {
                        int oo = o - 256;
                        int hd = oo >> 5, c = oo & 31;
                        int f = ((n >> 5) & 1) * 2 + (c >> 4);           // (sub, kh)
                        size_t idx = ((((size_t)(b * 8 + hd) * 16 + (n >> 6)) * 4 + f) * 64
                                      + ((c >> 3) & 1) * 32 + (n & 31)) * 8 + (c & 7);
                        kT_h[idx] = hh; kT_l[idx] = ll;
                    }
                }
            }
        }
    } else {
        #pragma unroll
        for (int i = 0; i < 4; i++) {
            #pragma unroll
            for (int r = 0; r < 4; r++) {
                int o = o0 + wr * 64 + i * 16 + lq * 4 + r;
                float sc = S[512 + o], sh = T[512 + o];
                #pragma unroll
                for (int j = 0; j < 4; j++) {
                    int n = n0 + wc * 64 + j * 16 + l16;
                    // PV-fragment order within each 64-key tile:
                    // chunk c4=(k>>2)&3 goes to slot {0,2,1,3}[c4]
                    int k = n & 63;
                    int s4 = k >> 4, c4 = (k >> 2) & 3;
                    int ep = s4 * 16 + (c4 & 1) * 8 + (c4 >> 1) * 4 + (k & 3);
                    int nst = (n & ~63) | ep;
                    vbuf[((size_t)(b * 1024) + o) * 1024 + nst] = (_Float16)(acc[i][j][r] * sc + sh);
                }
            }
        }
    }
}

// ---------------------------------------------------------------- attn
// Online-softmax flash attention with ONE-TILE-DEFERRED PV (in-wave software
// pipeline, T15): per iteration QK(kt) -> PV(kt-1) -> softmax(kt). The PV
// MFMAs are independent of QK's results, so they issue into QK's latency
// shadow and the softmax VALU overlaps PV's MFMA execution -- breaking the
// serial QK->softmax->PV chain that left both pipes <50% busy.
// 256 thr = 4 waves, 128 q/block, grid (bh=128, qt=8) = 1024 blocks.
// V TRIPLE-buffered (PV(kt-1) reads Vs[(kt-1)%3] while DMA(kt+1) writes
// Vs[(kt+1)%3]; disjoint mod 3, all other hazards barrier-separated).
// K double-buffered. LDS = 48K + 16K = 64K exactly -> 2 blocks/CU.
// All barriers block-uniform (16 total). Defer-max THR=8 gates the rescale.
__device__ __forceinline__ f32x16 qk6(f16x8 kh0, f16x8 kl0, f16x8 kh1, f16x8 kl1,
                                      f16x8 qh0, f16x8 ql0, f16x8 qh1, f16x8 ql1) {
    f32x16 c = {};
    c = __builtin_amdgcn_mfma_f32_32x32x16_f16(kh0, qh0, c, 0, 0, 0);
    c = __builtin_amdgcn_mfma_f32_32x32x16_f16(kl0, qh0, c, 0, 0, 0);
    c = __builtin_amdgcn_mfma_f32_32x32x16_f16(kh0, ql0, c, 0, 0, 0);
    c = __builtin_amdgcn_mfma_f32_32x32x16_f16(kh1, qh1, c, 0, 0, 0);
    c = __builtin_amdgcn_mfma_f32_32x32x16_f16(kl1, qh1, c, 0, 0, 0);
    c = __builtin_amdgcn_mfma_f32_32x32x16_f16(kh1, ql1, c, 0, 0, 0);
    return c;
}

__global__ __launch_bounds__(256, 2) void attn(
    const _Float16* __restrict__ qT_h, const _Float16* __restrict__ qT_l,
    const _Float16* __restrict__ kT_h, const _Float16* __restrict__ kT_l,
    const _Float16* __restrict__ vbuf,
    _Float16* __restrict__ xxT_h, _Float16* __restrict__ xxT_l)
{
    __shared__ __align__(16) _Float16 Vs[3][128 * 64];   // 48 KB (triple)
    __shared__ __align__(16) _Float16 Ksh[2][2048];      // 8 KB
    __shared__ __align__(16) _Float16 Ksl[2][2048];      // 8 KB
    const int t = threadIdx.x, lane = t & 63, w = t >> 6;
    const int L = lane & 31, hl = lane >> 5;
    const int bh = blockIdx.x, qt = blockIdx.y;
    const int b = bh >> 3, h = bh & 7;
    const size_t vbase = ((size_t)(b * 1024) + h * 128) * 1024;

    // Q B-frags (hi/lo planes); once per block
    f16x8 bq_h[2], bq_l[2];
    {
        int q = qt * 128 + w * 32 + L;
        #pragma unroll
        for (int kh = 0; kh < 2; kh++) {
            size_t base = ((size_t)(bh * 1024) + q) * 32 + kh * 16 + hl * 8;
            bq_h[kh] = *(const f16x8*)(qT_h + base);
            bq_l[kh] = *(const f16x8*)(qT_l + base);
        }
    }

    f32x16 o_acc[4] = {};
    float m_st = -INFINITY, l_st = 0.f;
    f16x8 pf[4];        // P(kt-1), consumed one iteration later

    #define DMA_TILE(vb, kb, kt_)                                                  \
        {                                                                          \
            size_t ktb = (size_t)(bh * 16 + (kt_)) * 2048 + (size_t)t * 8;         \
            __builtin_amdgcn_global_load_lds((gas_p)(const void*)(kT_h + ktb),     \
                                             (las_p)(void*)&Ksh[kb][w * 512], 16, 0, 0); \
            __builtin_amdgcn_global_load_lds((gas_p)(const void*)(kT_l + ktb),     \
                                             (las_p)(void*)&Ksl[kb][w * 512], 16, 0, 0); \
            _Pragma("unroll")                                                      \
            for (int p = 0; p < 4; p++) {                                          \
                int g2 = t + p * 256;                                              \
                int d = g2 >> 3;                                                   \
                int kcg = (g2 & 7) ^ (d & 7);                                      \
                const _Float16* src = vbuf + vbase + (size_t)d * 1024              \
                                      + (kt_) * 64 + kcg * 8;                      \
                _Float16* dst = &Vs[vb][(p * 256 + w * 64) * 8];                   \
                __builtin_amdgcn_global_load_lds((gas_p)(const void*)src,          \
                                                 (las_p)(void*)dst, 16, 0, 0);     \
            }                                                                      \
        }

    DMA_TILE(0, 0, 0)
    __syncthreads();

    for (int kt = 0; kt < 16; kt++) {
        const int kcur = kt & 1;
        const int vprv = (kt + 2) % 3;       // buffer holding tile kt-1

        if (kt < 15) DMA_TILE((kt + 1) % 3, kcur ^ 1, kt + 1)

        // K frags from LDS (lgkmcnt only -- DMA stays in flight)
        const _Float16* khp = &Ksh[kcur][lane * 8];
        const _Float16* klp = &Ksl[kcur][lane * 8];
        f16x8 K0h = *(const f16x8*)(khp);
        f16x8 K1h = *(const f16x8*)(khp + 512);
        f16x8 K2h = *(const f16x8*)(khp + 1024);
        f16x8 K3h = *(const f16x8*)(khp + 1536);
        f16x8 K0l = *(const f16x8*)(klp);
        f16x8 K1l = *(const f16x8*)(klp + 512);
        f16x8 K2l = *(const f16x8*)(klp + 1024);
        f16x8 K3l = *(const f16x8*)(klp + 1536);

        __builtin_amdgcn_s_setprio(1);
        f32x16 c0 = qk6(K0h, K0l, K1h, K1l, bq_h[0], bq_l[0], bq_h[1], bq_l[1]);
        f32x16 c1 = qk6(K2h, K2l, K3h, K3l, bq_h[0], bq_l[0], bq_h[1], bq_l[1]);
        __builtin_amdgcn_s_setprio(0);

        // ---- PV(kt-1): independent of c0/c1, fills QK's latency shadow ----
        if (kt) {
            __builtin_amdgcn_s_setprio(1);
            #pragma unroll
            for (int s = 0; s < 4; s++) {
                int cp = (2 * s + hl) ^ (L & 7);
                #pragma unroll
                for (int dt = 0; dt < 4; dt++) {
                    f16x8 avp = *(const f16x8*)(&Vs[vprv][(dt * 32 + L) * 64 + cp * 8]);
                    o_acc[dt] = __builtin_amdgcn_mfma_f32_32x32x16_f16(avp, pf[s], o_acc[dt], 0, 0, 0);
                }
            }
            __builtin_amdgcn_s_setprio(0);
        }

        // ---- softmax(kt): overlaps PV's MFMA execution ----
        // row-max via max3 fusion (fmaxf(fmaxf(a,b),c) -> v_max3_f32)
        #define EL(e) ((e) < 16 ? c0[e] : c1[(e) - 16])
        float t1[11];
        #pragma unroll
        for (int g = 0; g < 10; g++)
            t1[g] = fmaxf(fmaxf(EL(3 * g), EL(3 * g + 1)), EL(3 * g + 2));
        t1[10] = fmaxf(EL(30), EL(31));
        #undef EL
        float t2a = fmaxf(fmaxf(t1[0], t1[1]), t1[2]);
        float t2b = fmaxf(fmaxf(t1[3], t1[4]), t1[5]);
        float t2c = fmaxf(fmaxf(t1[6], t1[7]), t1[8]);
        float t2d = fmaxf(t1[9], t1[10]);
        float mx0 = fmaxf(fmaxf(t2a, t2b), fmaxf(t2c, t2d));
        float mx = fmaxf(mx0, __shfl_xor(mx0, 32, 64));

        // defer-max: only rescale when the row max grows by > 8 (p <= 2^8 in f16)
        if (__any(mx > m_st + 8.f)) {
            float mnew = fmaxf(m_st, mx);
            float a = exp2f(m_st - mnew);
            l_st *= a;
            #pragma unroll
            for (int dt = 0; dt < 4; dt++)
                #pragma unroll
                for (int i = 0; i < 16; i++) o_acc[dt][i] *= a;
            m_st = mnew;
        }

        // exp -> packed f16 (cvt_pkrtz), partial-sum trees; store into pf for
        // consumption NEXT iteration
        float rs = 0.f;
        #pragma unroll
        for (int s = 0; s < 4; s++) {
            float pv[8];
            #pragma unroll
            for (int j = 0; j < 8; j++) {
                float cv = (s < 2) ? c0[(s & 1) * 8 + j] : c1[(s & 1) * 8 + j];
                pv[j] = exp2f(cv - m_st);
            }
            rs += ((pv[0] + pv[1]) + (pv[2] + pv[3])) + ((pv[4] + pv[5]) + (pv[6] + pv[7]));
            union { f16x8 v; h16x2 hh[4]; } u;
            #pragma unroll
            for (int j = 0; j < 4; j++)
                u.hh[j] = __builtin_amdgcn_cvt_pkrtz(pv[2 * j], pv[2 * j + 1]);
            pf[s] = u.v;
        }
        l_st += rs;

        if (kt < 15) __syncthreads();   // drains this iter's DMA + joins waves
    }
    #undef DMA_TILE

    // epilogue PV(15): tile 15 lives in Vs[15 % 3 == 0]
    {
        __builtin_amdgcn_s_setprio(1);
        #pragma unroll
        for (int s = 0; s < 4; s++) {
            int cp = (2 * s + hl) ^ (L & 7);
            #pragma unroll
            for (int dt = 0; dt < 4; dt++) {
                f16x8 avp = *(const f16x8*)(&Vs[0][(dt * 32 + L) * 64 + cp * 8]);
                o_acc[dt] = __builtin_amdgcn_mfma_f32_32x32x16_f16(avp, pf[s], o_acc[dt], 0, 0, 0);
            }
        }
        __builtin_amdgcn_s_setprio(0);
    }

    l_st += __shfl_xor(l_st, 32, 64);

    // epilogue: normalize, split hi/lo, store xxT[b][n=q][d]
    {
        float rl = 1.f / l_st;
        int q = qt * 128 + w * 32 + L;
        #pragma unroll
        for (int dt = 0; dt < 4; dt++) {
            #pragma unroll
            for (int gg = 0; gg < 4; gg++) {
                f16x4 hv, lv;
                #pragma unroll
                for (int rr = 0; rr < 4; rr++) {
                    float v = o_acc[dt][gg * 4 + rr] * rl;
                    _Float16 hh = (_Float16)v;
                    hv[rr] = hh; lv[rr] = (_Float16)(v - (float)hh);
                }
                size_t o = ((size_t)(b * 1024) + q) * 1024 + h * 128 + dt * 32 + gg * 8 + hl * 4;
                *(f16x4*)(xxT_h + o) = hv;
                *(f16x4*)(xxT_l + o) = lv;
            }
        }
    }
}

// ---------------------------------------------------------------- gemm_out
// out[o][n] = (sum_c Wp[o,c]*xx[c,n]) * s + t, 2-term hi/lo on xx. fp32 out.
__global__ __launch_bounds__(256, 2) void gemm_out(
    const _Float16* __restrict__ wp_h,
    const _Float16* __restrict__ xxT_h, const _Float16* __restrict__ xxT_l,
    const float* __restrict__ S, const float* __restrict__ T,
    float* __restrict__ out)
{
    __shared__ __align__(16) _Float16 As[128 * 40];
    __shared__ __align__(16) _Float16 Bh[64 * 40];
    __shared__ __align__(16) _Float16 Bl[64 * 40];
    const int t = threadIdx.x, lane = t & 63, w = t >> 6;
    const int wr = w >> 1, wc = w & 1, l16 = lane & 15, lq = lane >> 4;
    const int o0 = blockIdx.x * 128, n0 = blockIdx.y * 64, b = blockIdx.z;

    f32x4 acc[4][2] = {};

    for (int kb = 0; kb < 1024; kb += 32) {
        __syncthreads();
        #pragma unroll
        for (int p = 0; p < 2; p++) {
            int g = t + p * 256, row = g >> 2, ch = g & 3;
            *(uint4*)(&As[row * 40 + ch * 8]) =
                *(const uint4*)(wp_h + (size_t)(o0 + row) * 1024 + kb + ch * 8);
        }
        {
            int row = t >> 2, ch = t & 3;
            size_t src = ((size_t)(b * 1024) + n0 + row) * 1024 + kb + ch * 8;
            *(uint4*)(&Bh[row * 40 + ch * 8]) = *(const uint4*)(xxT_h + src);
            *(uint4*)(&Bl[row * 40 + ch * 8]) = *(const uint4*)(xxT_l + src);
        }
        __syncthreads();

        f16x8 a[4], bh[2], bl[2];
        #pragma unroll
        for (int i = 0; i < 4; i++) a[i] = *(const f16x8*)(&As[(wr * 64 + i * 16 + l16) * 40 + lq * 8]);
        #pragma unroll
        for (int j = 0; j < 2; j++) {
            bh[j] = *(const f16x8*)(&Bh[(wc * 32 + j * 16 + l16) * 40 + lq * 8]);
            bl[j] = *(const f16x8*)(&Bl[(wc * 32 + j * 16 + l16) * 40 + lq * 8]);
        }
        #pragma unroll
        for (int i = 0; i < 4; i++)
            #pragma unroll
            for (int j = 0; j < 2; j++) {
                acc[i][j] = __builtin_amdgcn_mfma_f32_16x16x32_f16(a[i], bh[j], acc[i][j], 0, 0, 0);
                acc[i][j] = __builtin_amdgcn_mfma_f32_16x16x32_f16(a[i], bl[j], acc[i][j], 0, 0, 0);
            }
    }

    #pragma unroll
    for (int i = 0; i < 4; i++) {
        #pragma unroll
        for (int r = 0; r < 4; r++) {
            int o = o0 + wr * 64 + i * 16 + lq * 4 + r;
            float sc = S[o], sh = T[o];
            #pragma unroll
            for (int j = 0; j < 2; j++) {
                int n = n0 + wc * 32 + j * 16 + l16;
                out[((size_t)(b * 384) + o) * 1024 + n] = acc[i][j][r] * sc + sh;
            }
        }
    }
}

// ---------------------------------------------------------------- launch

extern "C" void kernel_launch(void* const* d_in, const int* in_sizes, int n_in,
                              void* d_out, int out_size, void* d_ws, size_t ws_size,
                              hipStream_t stream) {
    const float* x   = (const float*)d_in[0];
    const float* wq  = (const float*)d_in[1];
    const float* bnq = (const float*)d_in[2];
    const float* wk  = (const float*)d_in[3];
    const float* bnk = (const float*)d_in[4];
    const float* wv  = (const float*)d_in[5];
    const float* bnv = (const float*)d_in[6];
    const float* wp  = (const float*)d_in[7];
    const float* bnp = (const float*)d_in[8];
    float* out = (float*)d_out;
    (void)in_sizes; (void)n_in; (void)out_size; (void)ws_size;

    char* ws = (char*)d_ws;
    size_t off = 0;
    auto alloc = [&](size_t bytes) {
        void* p = ws + off;
        off = (off + bytes + 255) & ~(size_t)255;
        return p;
    };
    // --- region A: dead after gemm_qkv; reused as xxT_h (needs >= 33.56 MB) ---
    _Float16* xT_hi = (_Float16*)alloc((size_t)16 * 1024 * 384 * 2);   // 12.58 MB
    _Float16* xT_lo = (_Float16*)alloc((size_t)16 * 1024 * 384 * 2);   // 12.58 MB
    _Float16* wqk_h = (_Float16*)alloc((size_t)512 * 384 * 2);
    _Float16* wqk_l = (_Float16*)alloc((size_t)512 * 384 * 2);
    _Float16* wv_h  = (_Float16*)alloc((size_t)1024 * 384 * 2);
    alloc((size_t)7 * 1024 * 1024);                                     // pad region A to > 33.56 MB
    _Float16* xxT_h = (_Float16*)d_ws;                                  // alias over region A
    // --- live buffers ---
    _Float16* wp_h  = (_Float16*)alloc((size_t)384 * 1024 * 2);
    float*    s_qkv = (float*)alloc(1536 * 4);
    float*    t_qkv = (float*)alloc(1536 * 4);
    float*    s_p   = (float*)alloc(384 * 4);
    float*    t_p   = (float*)alloc(384 * 4);
    _Float16* qT_h  = (_Float16*)alloc((size_t)16 * 8 * 1024 * 32 * 2); // 8.39 MB
    _Float16* qT_l  = (_Float16*)alloc((size_t)16 * 8 * 1024 * 32 * 2); // 8.39 MB
    _Float16* kT_h  = (_Float16*)alloc((size_t)16 * 8 * 1024 * 32 * 2); // 8.39 MB
    _Float16* kT_l  = (_Float16*)alloc((size_t)16 * 8 * 1024 * 32 * 2); // 8.39 MB
    _Float16* vbuf  = (_Float16*)alloc((size_t)16 * 1024 * 1024 * 2);   // 33.55 MB
    _Float16* xxT_l = (_Float16*)alloc((size_t)16 * 1024 * 1024 * 2);   // 33.55 MB

    prep<<<dim3(6, 16, 17), dim3(256), 0, stream>>>(
        x, wq, wk, wv, wp, bnq, bnk, bnv, bnp,
        xT_hi, xT_lo, wqk_h, wqk_l, wv_h, wp_h, s_qkv, t_qkv, s_p, t_p);

    gemm_qkv<<<dim3(12, 8, 16), dim3(256), 0, stream>>>(
        wqk_h, wqk_l, wv_h, xT_hi, xT_lo, s_qkv, t_qkv,
        qT_h, qT_l, kT_h, kT_l, vbuf);

    attn<<<dim3(128, 8), dim3(256), 0, stream>>>(qT_h, qT_l, kT_h, kT_l, vbuf, xxT_h, xxT_l);

    gemm_out<<<dim3(3, 16, 16), dim3(256), 0, stream>>>(wp_h, xxT_h, xxT_l, s_p, t_p, out);
}

// Round 7
// 283.736 us; speedup vs baseline: 1.0959x; 1.0829x over previous
//
#include <hip/hip_runtime.h>

typedef _Float16 f16x8 __attribute__((ext_vector_type(8)));
typedef _Float16 f16x4 __attribute__((ext_vector_type(4)));
typedef __fp16 h16x2 __attribute__((ext_vector_type(2)));
typedef float f32x4 __attribute__((ext_vector_type(4)));
typedef float f32x16 __attribute__((ext_vector_type(16)));

#define BN_EPS 1e-5f
#define SQRT32 5.656854249492381f
#define LOG2E  1.4426950408889634f

typedef const __attribute__((address_space(1))) void* gas_p;
typedef __attribute__((address_space(3))) void* las_p;

// ---------------------------------------------------------------- prep (merged)
// z<16: x [b][c=384][n] fp32 -> xT_hi/lo [b][n][c] fp16 planes (transpose+split).
// z==16: weight conversion + BN affine fold.
__global__ __launch_bounds__(256) void prep(
    const float* __restrict__ x,
    const float* __restrict__ wq, const float* __restrict__ wk,
    const float* __restrict__ wv, const float* __restrict__ wp,
    const float* __restrict__ bnq, const float* __restrict__ bnk,
    const float* __restrict__ bnv, const float* __restrict__ bnp,
    _Float16* __restrict__ xT_hi, _Float16* __restrict__ xT_lo,
    _Float16* __restrict__ wqk_h, _Float16* __restrict__ wqk_l,
    _Float16* __restrict__ wv_h,  _Float16* __restrict__ wp_h,
    float* __restrict__ s_qkv, float* __restrict__ t_qkv,
    float* __restrict__ s_p,   float* __restrict__ t_p)
{
    __shared__ float Tx[64][65];
    const int t = threadIdx.x;
    if (blockIdx.z < 16) {
        const int ct = blockIdx.x, nt = blockIdx.y, b = blockIdx.z;
        const int c0 = ct * 64, n0 = nt * 64;
        {
            int tr = t >> 4, tc = (t & 15) * 4;
            #pragma unroll
            for (int p = 0; p < 4; p++) {
                int r = tr + p * 16;
                float4 v = *(const float4*)(x + ((size_t)(b * 384 + c0 + r)) * 1024 + n0 + tc);
                Tx[r][tc + 0] = v.x; Tx[r][tc + 1] = v.y; Tx[r][tc + 2] = v.z; Tx[r][tc + 3] = v.w;
            }
        }
        __syncthreads();
        {
            int nn = t >> 2, cc = (t & 3) * 16;
            f16x8 h0, h1, l0, l1;
            #pragma unroll
            for (int i = 0; i < 8; i++) {
                float v = Tx[cc + i][nn];
                _Float16 hh = (_Float16)v;
                h0[i] = hh; l0[i] = (_Float16)(v - (float)hh);
            }
            #pragma unroll
            for (int i = 0; i < 8; i++) {
                float v = Tx[cc + 8 + i][nn];
                _Float16 hh = (_Float16)v;
                h1[i] = hh; l1[i] = (_Float16)(v - (float)hh);
            }
            size_t o = ((size_t)(b * 1024 + n0 + nn)) * 384 + c0 + cc;
            *(f16x8*)(xT_hi + o) = h0; *(f16x8*)(xT_hi + o + 8) = h1;
            *(f16x8*)(xT_lo + o) = l0; *(f16x8*)(xT_lo + o + 8) = l1;
        }
    } else {
        const int NQK = 512 * 384, NV = 1024 * 384, NP = 384 * 1024;
        int tid = (blockIdx.y * 6 + blockIdx.x) * 256 + t;       // 0..24575
        for (int i = tid; i < NQK + NV + NP; i += 24576) {
            if (i < NQK) {
                int o = i / 384, c = i - o * 384;
                float v = (o < 256) ? wq[o * 384 + c] : wk[(o - 256) * 384 + c];
                _Float16 hh = (_Float16)v;
                wqk_h[i] = hh; wqk_l[i] = (_Float16)(v - (float)hh);
            } else if (i < NQK + NV) {
                wv_h[i - NQK] = (_Float16)wv[i - NQK];
            } else {
                wp_h[i - NQK - NV] = (_Float16)wp[i - NQK - NV];
            }
        }
        if (tid < 1536) {
            int i = tid;
            float g, be, m, v;
            if (i < 256)      { int o = i;       g = bnq[o]; be = bnq[256 + o];  m = bnq[512 + o];  v = bnq[768 + o]; }
            else if (i < 512) { int o = i - 256; g = bnk[o]; be = bnk[256 + o];  m = bnk[512 + o];  v = bnk[768 + o]; }
            else              { int o = i - 512; g = bnv[o]; be = bnv[1024 + o]; m = bnv[2048 + o]; v = bnv[3072 + o]; }
            float s = g * rsqrtf(v + BN_EPS);
            float tt = be - m * s;
            // fold /scale (= *sqrt(kd)) AND log2(e) (exp2 softmax) into Q's affine
            if (i < 256) { s *= SQRT32 * LOG2E; tt *= SQRT32 * LOG2E; }
            s_qkv[i] = s; t_qkv[i] = tt;
        } else if (tid < 1536 + 384) {
            int o = tid - 1536;
            float g = bnp[o], be = bnp[384 + o], m = bnp[768 + o], v = bnp[1152 + o];
            float s = g * rsqrtf(v + BN_EPS);
            s_p[o] = s; t_p[o] = be - m * s;
        }
    }
}

// ---------------------------------------------------------------- gemm_qkv
// m97-style staging: BK=64, linear LDS [rows][64] fp16, global_load_lds
// width-16 with PER-LANE PRE-SWIZZLED global source (16B slot ^= row&7),
// ds_read_b128 fragment reads apply the same XOR -> conflict-free (T2).
// bx<4 (Q/K rows): D[n][o] (3-term hi/lo); qT [b][h][n][32] planes; kT in
// frag-linear layout so attn's K DMA is a contiguous 4KB copy.
// bx>=4 (V rows): D[o][n] 1-term; vbuf in PV-fragment order for attn.
__global__ __launch_bounds__(256, 2) void gemm_qkv(
    const _Float16* __restrict__ wqk_h, const _Float16* __restrict__ wqk_l,
    const _Float16* __restrict__ wv_h,
    const _Float16* __restrict__ xT_hi, const _Float16* __restrict__ xT_lo,
    const float* __restrict__ S, const float* __restrict__ T,
    _Float16* __restrict__ qT_h, _Float16* __restrict__ qT_l,
    _Float16* __restrict__ kT_h, _Float16* __restrict__ kT_l,
    _Float16* __restrict__ vbuf)
{
    __shared__ __align__(16) _Float16 As_h[128 * 64];   // 16 KB each
    __shared__ __align__(16) _Float16 As_l[128 * 64];
    __shared__ __align__(16) _Float16 Bs_h[128 * 64];
    __shared__ __align__(16) _Float16 Bs_l[128 * 64];
    const int t = threadIdx.x, lane = t & 63, w = t >> 6;
    const int wr = w >> 1, wc = w & 1, l16 = lane & 15, lq = lane >> 4;
    const int bx = blockIdx.x, n0 = blockIdx.y * 128, b = blockIdx.z;
    const bool isv = bx >= 4;
    const int o0 = isv ? (bx - 4) * 128 : bx * 128;
    const _Float16* __restrict__ Ah = isv ? wv_h : wqk_h;

    f32x4 acc[4][4] = {};

    for (int kb = 0; kb < 384; kb += 64) {
        __syncthreads();
        // stage via global_load_lds: lane g writes LDS slot g; fetches the
        // swizzled source column so LDS[row][s] = global[row][s^(row&7)]
        #pragma unroll
        for (int p = 0; p < 4; p++) {
            int g = t + p * 256, row = g >> 3, s = g & 7;
            int col = ((s ^ (row & 7)) * 8);
            __builtin_amdgcn_global_load_lds(
                (gas_p)(const void*)(Ah + (size_t)(o0 + row) * 384 + kb + col),
                (las_p)(void*)&As_h[(p * 256 + w * 64) * 8], 16, 0, 0);
        }
        #pragma unroll
        for (int p = 0; p < 4; p++) {
            int g = t + p * 256, row = g >> 3, s = g & 7;
            int col = ((s ^ (row & 7)) * 8);
            __builtin_amdgcn_global_load_lds(
                (gas_p)(const void*)(xT_hi + ((size_t)(b * 1024) + n0 + row) * 384 + kb + col),
                (las_p)(void*)&Bs_h[(p * 256 + w * 64) * 8], 16, 0, 0);
        }
        if (!isv) {
            #pragma unroll
            for (int p = 0; p < 4; p++) {
                int g = t + p * 256, row = g >> 3, s = g & 7;
                int col = ((s ^ (row & 7)) * 8);
                __builtin_amdgcn_global_load_lds(
                    (gas_p)(const void*)(wqk_l + (size_t)(o0 + row) * 384 + kb + col),
                    (las_p)(void*)&As_l[(p * 256 + w * 64) * 8], 16, 0, 0);
            }
            #pragma unroll
            for (int p = 0; p < 4; p++) {
                int g = t + p * 256, row = g >> 3, s = g & 7;
                int col = ((s ^ (row & 7)) * 8);
                __builtin_amdgcn_global_load_lds(
                    (gas_p)(const void*)(xT_lo + ((size_t)(b * 1024) + n0 + row) * 384 + kb + col),
                    (las_p)(void*)&Bs_l[(p * 256 + w * 64) * 8], 16, 0, 0);
            }
        }
        __syncthreads();   // drains DMA (vmcnt 0) + joins waves

        if (!isv) {
            // transposed: A = x tiles (n rows), B = w tiles (o cols)
            #pragma unroll
            for (int kk = 0; kk < 2; kk++) {
                const int sl = ((kk * 4 + lq) ^ (l16 & 7)) * 8;
                f16x8 ah[4], al[4], bh[4], bl[4];
                #pragma unroll
                for (int i = 0; i < 4; i++) {
                    int row = wr * 64 + i * 16 + l16;
                    ah[i] = *(const f16x8*)(&Bs_h[row * 64 + sl]);
                    al[i] = *(const f16x8*)(&Bs_l[row * 64 + sl]);
                }
                #pragma unroll
                for (int j = 0; j < 4; j++) {
                    int row = wc * 64 + j * 16 + l16;
                    bh[j] = *(const f16x8*)(&As_h[row * 64 + sl]);
                    bl[j] = *(const f16x8*)(&As_l[row * 64 + sl]);
                }
                #pragma unroll
                for (int i = 0; i < 4; i++)
                    #pragma unroll
                    for (int j = 0; j < 4; j++) {
                        acc[i][j] = __builtin_amdgcn_mfma_f32_16x16x32_f16(ah[i], bh[j], acc[i][j], 0, 0, 0);
                        acc[i][j] = __builtin_amdgcn_mfma_f32_16x16x32_f16(al[i], bh[j], acc[i][j], 0, 0, 0);
                        acc[i][j] = __builtin_amdgcn_mfma_f32_16x16x32_f16(ah[i], bl[j], acc[i][j], 0, 0, 0);
                    }
            }
        } else {
            #pragma unroll
            for (int kk = 0; kk < 2; kk++) {
                const int sl = ((kk * 4 + lq) ^ (l16 & 7)) * 8;
                f16x8 a[4], bf[4];
                #pragma unroll
                for (int i = 0; i < 4; i++)
                    a[i] = *(const f16x8*)(&As_h[(wr * 64 + i * 16 + l16) * 64 + sl]);
                #pragma unroll
                for (int j = 0; j < 4; j++)
                    bf[j] = *(const f16x8*)(&Bs_h[(wc * 64 + j * 16 + l16) * 64 + sl]);
                #pragma unroll
                for (int i = 0; i < 4; i++)
                    #pragma unroll
                    for (int j = 0; j < 4; j++)
                        acc[i][j] = __builtin_amdgcn_mfma_f32_16x16x32_f16(a[i], bf[j], acc[i][j], 0, 0, 0);
            }
        }
    }

    if (!isv) {
        // D[n][o]: row = n, col(l16) = o.
        #pragma unroll
        for (int i = 0; i < 4; i++) {
            #pragma unroll
            for (int r = 0; r < 4; r++) {
                int n = n0 + wr * 64 + i * 16 + lq * 4 + r;
                #pragma unroll
                for (int j = 0; j < 4; j++) {
                    int o = o0 + wc * 64 + j * 16 + l16;
                    float sc = S[o], sh = T[o];
                    float v = acc[i][j][r] * sc + sh;
                    _Float16 hh = (_Float16)v;
                    _Float16 ll = (_Float16)(v - (float)hh);
                    if (o < 256) {
                        size_t idx = (((size_t)(b * 8) + (o >> 5)) * 1024 + n) * 32 + (o & 31);
                        qT_h[idx] = hh; qT_l[idx] = ll;
                    } else {
                        int oo = o - 256;
                        int hd = oo >> 5, c = oo & 31;
                        int f = ((n >> 5) & 1) * 2 + (c >> 4);           // (sub, kh)
                        size_t idx = ((((size_t)(b * 8 + hd) * 16 + (n >> 6)) * 4 + f) * 64
                                      + ((c >> 3) & 1) * 32 + (n & 31)) * 8 + (c & 7);
                        kT_h[idx] = hh; kT_l[idx] = ll;
                    }
                }
            }
        }
    } else {
        #pragma unroll
        for (int i = 0; i < 4; i++) {
            #pragma unroll
            for (int r = 0; r < 4; r++) {
                int o = o0 + wr * 64 + i * 16 + lq * 4 + r;
                float sc = S[512 + o], sh = T[512 + o];
                #pragma unroll
                for (int j = 0; j < 4; j++) {
                    int n = n0 + wc * 64 + j * 16 + l16;
                    // PV-fragment order within each 64-key tile:
                    // chunk c4=(k>>2)&3 goes to slot {0,2,1,3}[c4]
                    int k = n & 63;
                    int s4 = k >> 4, c4 = (k >> 2) & 3;
                    int ep = s4 * 16 + (c4 & 1) * 8 + (c4 >> 1) * 4 + (k & 3);
                    int nst = (n & ~63) | ep;
                    vbuf[((size_t)(b * 1024) + o) * 1024 + nst] = (_Float16)(acc[i][j][r] * sc + sh);
                }
            }
        }
    }
}

// ---------------------------------------------------------------- attn
// (unchanged from round 6 -- best verified 106.8 us)
// Online-softmax flash attention with one-tile-deferred PV; V triple-buffered,
// K double-buffered via global_load_lds; defer-max THR=8.
__device__ __forceinline__ f32x16 qk6(f16x8 kh0, f16x8 kl0, f16x8 kh1, f16x8 kl1,
                                      f16x8 qh0, f16x8 ql0, f16x8 qh1, f16x8 ql1) {
    f32x16 c = {};
    c = __builtin_amdgcn_mfma_f32_32x32x16_f16(kh0, qh0, c, 0, 0, 0);
    c = __builtin_amdgcn_mfma_f32_32x32x16_f16(kl0, qh0, c, 0, 0, 0);
    c = __builtin_amdgcn_mfma_f32_32x32x16_f16(kh0, ql0, c, 0, 0, 0);
    c = __builtin_amdgcn_mfma_f32_32x32x16_f16(kh1, qh1, c, 0, 0, 0);
    c = __builtin_amdgcn_mfma_f32_32x32x16_f16(kl1, qh1, c, 0, 0, 0);
    c = __builtin_amdgcn_mfma_f32_32x32x16_f16(kh1, ql1, c, 0, 0, 0);
    return c;
}

__global__ __launch_bounds__(256, 2) void attn(
    const _Float16* __restrict__ qT_h, const _Float16* __restrict__ qT_l,
    const _Float16* __restrict__ kT_h, const _Float16* __restrict__ kT_l,
    const _Float16* __restrict__ vbuf,
    _Float16* __restrict__ xxT_h, _Float16* __restrict__ xxT_l)
{
    __shared__ __align__(16) _Float16 Vs[3][128 * 64];   // 48 KB (triple)
    __shared__ __align__(16) _Float16 Ksh[2][2048];      // 8 KB
    __shared__ __align__(16) _Float16 Ksl[2][2048];      // 8 KB
    const int t = threadIdx.x, lane = t & 63, w = t >> 6;
    const int L = lane & 31, hl = lane >> 5;
    const int bh = blockIdx.x, qt = blockIdx.y;
    const int b = bh >> 3, h = bh & 7;
    const size_t vbase = ((size_t)(b * 1024) + h * 128) * 1024;

    // Q B-frags (hi/lo planes); once per block
    f16x8 bq_h[2], bq_l[2];
    {
        int q = qt * 128 + w * 32 + L;
        #pragma unroll
        for (int kh = 0; kh < 2; kh++) {
            size_t base = ((size_t)(bh * 1024) + q) * 32 + kh * 16 + hl * 8;
            bq_h[kh] = *(const f16x8*)(qT_h + base);
            bq_l[kh] = *(const f16x8*)(qT_l + base);
        }
    }

    f32x16 o_acc[4] = {};
    float m_st = -INFINITY, l_st = 0.f;
    f16x8 pf[4];        // P(kt-1), consumed one iteration later

    #define DMA_TILE(vb, kb, kt_)                                                  \
        {                                                                          \
            size_t ktb = (size_t)(bh * 16 + (kt_)) * 2048 + (size_t)t * 8;         \
            __builtin_amdgcn_global_load_lds((gas_p)(const void*)(kT_h + ktb),     \
                                             (las_p)(void*)&Ksh[kb][w * 512], 16, 0, 0); \
            __builtin_amdgcn_global_load_lds((gas_p)(const void*)(kT_l + ktb),     \
                                             (las_p)(void*)&Ksl[kb][w * 512], 16, 0, 0); \
            _Pragma("unroll")                                                      \
            for (int p = 0; p < 4; p++) {                                          \
                int g2 = t + p * 256;                                              \
                int d = g2 >> 3;                                                   \
                int kcg = (g2 & 7) ^ (d & 7);                                      \
                const _Float16* src = vbuf + vbase + (size_t)d * 1024              \
                                      + (kt_) * 64 + kcg * 8;                      \
                _Float16* dst = &Vs[vb][(p * 256 + w * 64) * 8];                   \
                __builtin_amdgcn_global_load_lds((gas_p)(const void*)src,          \
                                                 (las_p)(void*)dst, 16, 0, 0);     \
            }                                                                      \
        }

    DMA_TILE(0, 0, 0)
    __syncthreads();

    for (int kt = 0; kt < 16; kt++) {
        const int kcur = kt & 1;
        const int vprv = (kt + 2) % 3;       // buffer holding tile kt-1

        if (kt < 15) DMA_TILE((kt + 1) % 3, kcur ^ 1, kt + 1)

        // K frags from LDS (lgkmcnt only -- DMA stays in flight)
        const _Float16* khp = &Ksh[kcur][lane * 8];
        const _Float16* klp = &Ksl[kcur][lane * 8];
        f16x8 K0h = *(const f16x8*)(khp);
        f16x8 K1h = *(const f16x8*)(khp + 512);
        f16x8 K2h = *(const f16x8*)(khp + 1024);
        f16x8 K3h = *(const f16x8*)(khp + 1536);
        f16x8 K0l = *(const f16x8*)(klp);
        f16x8 K1l = *(const f16x8*)(klp + 512);
        f16x8 K2l = *(const f16x8*)(klp + 1024);
        f16x8 K3l = *(const f16x8*)(klp + 1536);

        __builtin_amdgcn_s_setprio(1);
        f32x16 c0 = qk6(K0h, K0l, K1h, K1l, bq_h[0], bq_l[0], bq_h[1], bq_l[1]);
        f32x16 c1 = qk6(K2h, K2l, K3h, K3l, bq_h[0], bq_l[0], bq_h[1], bq_l[1]);
        __builtin_amdgcn_s_setprio(0);

        // ---- PV(kt-1): independent of c0/c1, fills QK's latency shadow ----
        if (kt) {
            __builtin_amdgcn_s_setprio(1);
            #pragma unroll
            for (int s = 0; s < 4; s++) {
                int cp = (2 * s + hl) ^ (L & 7);
                #pragma unroll
                for (int dt = 0; dt < 4; dt++) {
                    f16x8 avp = *(const f16x8*)(&Vs[vprv][(dt * 32 + L) * 64 + cp * 8]);
                    o_acc[dt] = __builtin_amdgcn_mfma_f32_32x32x16_f16(avp, pf[s], o_acc[dt], 0, 0, 0);
                }
            }
            __builtin_amdgcn_s_setprio(0);
        }

        // ---- softmax(kt): overlaps PV's MFMA execution ----
        // row-max via max3 fusion (fmaxf(fmaxf(a,b),c) -> v_max3_f32)
        #define EL(e) ((e) < 16 ? c0[e] : c1[(e) - 16])
        float t1[11];
        #pragma unroll
        for (int g = 0; g < 10; g++)
            t1[g] = fmaxf(fmaxf(EL(3 * g), EL(3 * g + 1)), EL(3 * g + 2));
        t1[10] = fmaxf(EL(30), EL(31));
        #undef EL
        float t2a = fmaxf(fmaxf(t1[0], t1[1]), t1[2]);
        float t2b = fmaxf(fmaxf(t1[3], t1[4]), t1[5]);
        float t2c = fmaxf(fmaxf(t1[6], t1[7]), t1[8]);
        float t2d = fmaxf(t1[9], t1[10]);
        float mx0 = fmaxf(fmaxf(t2a, t2b), fmaxf(t2c, t2d));
        float mx = fmaxf(mx0, __shfl_xor(mx0, 32, 64));

        // defer-max: only rescale when the row max grows by > 8 (p <= 2^8 in f16)
        if (__any(mx > m_st + 8.f)) {
            float mnew = fmaxf(m_st, mx);
            float a = exp2f(m_st - mnew);
            l_st *= a;
            #pragma unroll
            for (int dt = 0; dt < 4; dt++)
                #pragma unroll
                for (int i = 0; i < 16; i++) o_acc[dt][i] *= a;
            m_st = mnew;
        }

        // exp -> packed f16 (cvt_pkrtz), partial-sum trees; store into pf for
        // consumption NEXT iteration
        float rs = 0.f;
        #pragma unroll
        for (int s = 0; s < 4; s++) {
            float pv[8];
            #pragma unroll
            for (int j = 0; j < 8; j++) {
                float cv = (s < 2) ? c0[(s & 1) * 8 + j] : c1[(s & 1) * 8 + j];
                pv[j] = exp2f(cv - m_st);
            }
            rs += ((pv[0] + pv[1]) + (pv[2] + pv[3])) + ((pv[4] + pv[5]) + (pv[6] + pv[7]));
            union { f16x8 v; h16x2 hh[4]; } u;
            #pragma unroll
            for (int j = 0; j < 4; j++)
                u.hh[j] = __builtin_amdgcn_cvt_pkrtz(pv[2 * j], pv[2 * j + 1]);
            pf[s] = u.v;
        }
        l_st += rs;

        if (kt < 15) __syncthreads();   // drains this iter's DMA + joins waves
    }
    #undef DMA_TILE

    // epilogue PV(15): tile 15 lives in Vs[15 % 3 == 0]
    {
        __builtin_amdgcn_s_setprio(1);
        #pragma unroll
        for (int s = 0; s < 4; s++) {
            int cp = (2 * s + hl) ^ (L & 7);
            #pragma unroll
            for (int dt = 0; dt < 4; dt++) {
                f16x8 avp = *(const f16x8*)(&Vs[0][(dt * 32 + L) * 64 + cp * 8]);
                o_acc[dt] = __builtin_amdgcn_mfma_f32_32x32x16_f16(avp, pf[s], o_acc[dt], 0, 0, 0);
            }
        }
        __builtin_amdgcn_s_setprio(0);
    }

    l_st += __shfl_xor(l_st, 32, 64);

    // epilogue: normalize, split hi/lo, store xxT[b][n=q][d]
    {
        float rl = 1.f / l_st;
        int q = qt * 128 + w * 32 + L;
        #pragma unroll
        for (int dt = 0; dt < 4; dt++) {
            #pragma unroll
            for (int gg = 0; gg < 4; gg++) {
                f16x4 hv, lv;
                #pragma unroll
                for (int rr = 0; rr < 4; rr++) {
                    float v = o_acc[dt][gg * 4 + rr] * rl;
                    _Float16 hh = (_Float16)v;
                    hv[rr] = hh; lv[rr] = (_Float16)(v - (float)hh);
                }
                size_t o = ((size_t)(b * 1024) + q) * 1024 + h * 128 + dt * 32 + gg * 8 + hl * 4;
                *(f16x4*)(xxT_h + o) = hv;
                *(f16x4*)(xxT_l + o) = lv;
            }
        }
    }
}

// ---------------------------------------------------------------- gemm_out
// m97-style staging (same recipe as gemm_qkv): BK=64, linear LDS,
// global_load_lds with pre-swizzled source, swizzled ds_read_b128.
// out[o][n] = (sum_c Wp[o,c]*xx[c,n]) * s + t, 2-term hi/lo on xx. fp32 out.
__global__ __launch_bounds__(256, 2) void gemm_out(
    const _Float16* __restrict__ wp_h,
    const _Float16* __restrict__ xxT_h, const _Float16* __restrict__ xxT_l,
    const float* __restrict__ S, const float* __restrict__ T,
    float* __restrict__ out)
{
    __shared__ __align__(16) _Float16 As[128 * 64];   // 16 KB
    __shared__ __align__(16) _Float16 Bh[64 * 64];    // 8 KB
    __shared__ __align__(16) _Float16 Bl[64 * 64];    // 8 KB
    const int t = threadIdx.x, lane = t & 63, w = t >> 6;
    const int wr = w >> 1, wc = w & 1, l16 = lane & 15, lq = lane >> 4;
    const int o0 = blockIdx.x * 128, n0 = blockIdx.y * 64, b = blockIdx.z;

    f32x4 acc[4][2] = {};

    for (int kb = 0; kb < 1024; kb += 64) {
        __syncthreads();
        #pragma unroll
        for (int p = 0; p < 4; p++) {
            int g = t + p * 256, row = g >> 3, s = g & 7;
            int col = ((s ^ (row & 7)) * 8);
            __builtin_amdgcn_global_load_lds(
                (gas_p)(const void*)(wp_h + (size_t)(o0 + row) * 1024 + kb + col),
                (las_p)(void*)&As[(p * 256 + w * 64) * 8], 16, 0, 0);
        }
        #pragma unroll
        for (int p = 0; p < 2; p++) {
            int g = t + p * 256, row = g >> 3, s = g & 7;
            int col = ((s ^ (row & 7)) * 8);
            size_t src = ((size_t)(b * 1024) + n0 + row) * 1024 + kb + col;
            __builtin_amdgcn_global_load_lds(
                (gas_p)(const void*)(xxT_h + src),
                (las_p)(void*)&Bh[(p * 256 + w * 64) * 8], 16, 0, 0);
            __builtin_amdgcn_global_load_lds(
                (gas_p)(const void*)(xxT_l + src),
                (las_p)(void*)&Bl[(p * 256 + w * 64) * 8], 16, 0, 0);
        }
        __syncthreads();

        #pragma unroll
        for (int kk = 0; kk < 2; kk++) {
            const int sl = ((kk * 4 + lq) ^ (l16 & 7)) * 8;
            f16x8 a[4], bh2[2], bl2[2];
            #pragma unroll
            for (int i = 0; i < 4; i++)
                a[i] = *(const f16x8*)(&As[(wr * 64 + i * 16 + l16) * 64 + sl]);
            #pragma unroll
            for (int j = 0; j < 2; j++) {
                int row = wc * 32 + j * 16 + l16;
                bh2[j] = *(const f16x8*)(&Bh[row * 64 + sl]);
                bl2[j] = *(const f16x8*)(&Bl[row * 64 + sl]);
            }
            #pragma unroll
            for (int i = 0; i < 4; i++)
                #pragma unroll
                for (int j = 0; j < 2; j++) {
                    acc[i][j] = __builtin_amdgcn_mfma_f32_16x16x32_f16(a[i], bh2[j], acc[i][j], 0, 0, 0);
                    acc[i][j] = __builtin_amdgcn_mfma_f32_16x16x32_f16(a[i], bl2[j], acc[i][j], 0, 0, 0);
                }
        }
    }

    #pragma unroll
    for (int i = 0; i < 4; i++) {
        #pragma unroll
        for (int r = 0; r < 4; r++) {
            int o = o0 + wr * 64 + i * 16 + lq * 4 + r;
            float sc = S[o], sh = T[o];
            #pragma unroll
            for (int j = 0; j < 2; j++) {
                int n = n0 + wc * 32 + j * 16 + l16;
                out[((size_t)(b * 384) + o) * 1024 + n] = acc[i][j][r] * sc + sh;
            }
        }
    }
}

// ---------------------------------------------------------------- launch

extern "C" void kernel_launch(void* const* d_in, const int* in_sizes, int n_in,
                              void* d_out, int out_size, void* d_ws, size_t ws_size,
                              hipStream_t stream) {
    const float* x   = (const float*)d_in[0];
    const float* wq  = (const float*)d_in[1];
    const float* bnq = (const float*)d_in[2];
    const float* wk  = (const float*)d_in[3];
    const float* bnk = (const float*)d_in[4];
    const float* wv  = (const float*)d_in[5];
    const float* bnv = (const float*)d_in[6];
    const float* wp  = (const float*)d_in[7];
    const float* bnp = (const float*)d_in[8];
    float* out = (float*)d_out;
    (void)in_sizes; (void)n_in; (void)out_size; (void)ws_size;

    char* ws = (char*)d_ws;
    size_t off = 0;
    auto alloc = [&](size_t bytes) {
        void* p = ws + off;
        off = (off + bytes + 255) & ~(size_t)255;
        return p;
    };
    // --- region A: dead after gemm_qkv; reused as xxT_h (needs >= 33.56 MB) ---
    _Float16* xT_hi = (_Float16*)alloc((size_t)16 * 1024 * 384 * 2);   // 12.58 MB
    _Float16* xT_lo = (_Float16*)alloc((size_t)16 * 1024 * 384 * 2);   // 12.58 MB
    _Float16* wqk_h = (_Float16*)alloc((size_t)512 * 384 * 2);
    _Float16* wqk_l = (_Float16*)alloc((size_t)512 * 384 * 2);
    _Float16* wv_h  = (_Float16*)alloc((size_t)1024 * 384 * 2);
    alloc((size_t)7 * 1024 * 1024);                                     // pad region A to > 33.56 MB
    _Float16* xxT_h = (_Float16*)d_ws;                                  // alias over region A
    // --- live buffers ---
    _Float16* wp_h  = (_Float16*)alloc((size_t)384 * 1024 * 2);
    float*    s_qkv = (float*)alloc(1536 * 4);
    float*    t_qkv = (float*)alloc(1536 * 4);
    float*    s_p   = (float*)alloc(384 * 4);
    float*    t_p   = (float*)alloc(384 * 4);
    _Float16* qT_h  = (_Float16*)alloc((size_t)16 * 8 * 1024 * 32 * 2); // 8.39 MB
    _Float16* qT_l  = (_Float16*)alloc((size_t)16 * 8 * 1024 * 32 * 2); // 8.39 MB
    _Float16* kT_h  = (_Float16*)alloc((size_t)16 * 8 * 1024 * 32 * 2); // 8.39 MB
    _Float16* kT_l  = (_Float16*)alloc((size_t)16 * 8 * 1024 * 32 * 2); // 8.39 MB
    _Float16* vbuf  = (_Float16*)alloc((size_t)16 * 1024 * 1024 * 2);   // 33.55 MB
    _Float16* xxT_l = (_Float16*)alloc((size_t)16 * 1024 * 1024 * 2);   // 33.55 MB

    prep<<<dim3(6, 16, 17), dim3(256), 0, stream>>>(
        x, wq, wk, wv, wp, bnq, bnk, bnv, bnp,
        xT_hi, xT_lo, wqk_h, wqk_l, wv_h, wp_h, s_qkv, t_qkv, s_p, t_p);

    gemm_qkv<<<dim3(12, 8, 16), dim3(256), 0, stream>>>(
        wqk_h, wqk_l, wv_h, xT_hi, xT_lo, s_qkv, t_qkv,
        qT_h, qT_l, kT_h, kT_l, vbuf);

    attn<<<dim3(128, 8), dim3(256), 0, stream>>>(qT_h, qT_l, kT_h, kT_l, vbuf, xxT_h, xxT_l);

    gemm_out<<<dim3(3, 16, 16), dim3(256), 0, stream>>>(wp_h, xxT_h, xxT_l, s_p, t_p, out);
}

// Round 8
// 283.505 us; speedup vs baseline: 1.0968x; 1.0008x over previous
//
#include <hip/hip_runtime.h>

typedef _Float16 f16x8 __attribute__((ext_vector_type(8)));
typedef _Float16 f16x4 __attribute__((ext_vector_type(4)));
typedef __fp16 h16x2 __attribute__((ext_vector_type(2)));
typedef float f32x4 __attribute__((ext_vector_type(4)));
typedef float f32x16 __attribute__((ext_vector_type(16)));

#define BN_EPS 1e-5f
#define SQRT32 5.656854249492381f
#define LOG2E  1.4426950408889634f

typedef const __attribute__((address_space(1))) void* gas_p;
typedef __attribute__((address_space(3))) void* las_p;

// ---------------------------------------------------------------- prep (merged)
// z<16: x [b][c=384][n] fp32 -> xT_hi/lo [b][n][c] fp16 planes (transpose+split).
// z==16: weight conversion + BN affine fold.
__global__ __launch_bounds__(256) void prep(
    const float* __restrict__ x,
    const float* __restrict__ wq, const float* __restrict__ wk,
    const float* __restrict__ wv, const float* __restrict__ wp,
    const float* __restrict__ bnq, const float* __restrict__ bnk,
    const float* __restrict__ bnv, const float* __restrict__ bnp,
    _Float16* __restrict__ xT_hi, _Float16* __restrict__ xT_lo,
    _Float16* __restrict__ wqk_h, _Float16* __restrict__ wqk_l,
    _Float16* __restrict__ wv_h,  _Float16* __restrict__ wp_h,
    float* __restrict__ s_qkv, float* __restrict__ t_qkv,
    float* __restrict__ s_p,   float* __restrict__ t_p)
{
    __shared__ float Tx[64][65];
    const int t = threadIdx.x;
    if (blockIdx.z < 16) {
        const int ct = blockIdx.x, nt = blockIdx.y, b = blockIdx.z;
        const int c0 = ct * 64, n0 = nt * 64;
        {
            int tr = t >> 4, tc = (t & 15) * 4;
            #pragma unroll
            for (int p = 0; p < 4; p++) {
                int r = tr + p * 16;
                float4 v = *(const float4*)(x + ((size_t)(b * 384 + c0 + r)) * 1024 + n0 + tc);
                Tx[r][tc + 0] = v.x; Tx[r][tc + 1] = v.y; Tx[r][tc + 2] = v.z; Tx[r][tc + 3] = v.w;
            }
        }
        __syncthreads();
        {
            int nn = t >> 2, cc = (t & 3) * 16;
            f16x8 h0, h1, l0, l1;
            #pragma unroll
            for (int i = 0; i < 8; i++) {
                float v = Tx[cc + i][nn];
                _Float16 hh = (_Float16)v;
                h0[i] = hh; l0[i] = (_Float16)(v - (float)hh);
            }
            #pragma unroll
            for (int i = 0; i < 8; i++) {
                float v = Tx[cc + 8 + i][nn];
                _Float16 hh = (_Float16)v;
                h1[i] = hh; l1[i] = (_Float16)(v - (float)hh);
            }
            size_t o = ((size_t)(b * 1024 + n0 + nn)) * 384 + c0 + cc;
            *(f16x8*)(xT_hi + o) = h0; *(f16x8*)(xT_hi + o + 8) = h1;
            *(f16x8*)(xT_lo + o) = l0; *(f16x8*)(xT_lo + o + 8) = l1;
        }
    } else {
        const int NQK = 512 * 384, NV = 1024 * 384, NP = 384 * 1024;
        int tid = (blockIdx.y * 6 + blockIdx.x) * 256 + t;       // 0..24575
        for (int i = tid; i < NQK + NV + NP; i += 24576) {
            if (i < NQK) {
                int o = i / 384, c = i - o * 384;
                float v = (o < 256) ? wq[o * 384 + c] : wk[(o - 256) * 384 + c];
                _Float16 hh = (_Float16)v;
                wqk_h[i] = hh; wqk_l[i] = (_Float16)(v - (float)hh);
            } else if (i < NQK + NV) {
                wv_h[i - NQK] = (_Float16)wv[i - NQK];
            } else {
                wp_h[i - NQK - NV] = (_Float16)wp[i - NQK - NV];
            }
        }
        if (tid < 1536) {
            int i = tid;
            float g, be, m, v;
            if (i < 256)      { int o = i;       g = bnq[o]; be = bnq[256 + o];  m = bnq[512 + o];  v = bnq[768 + o]; }
            else if (i < 512) { int o = i - 256; g = bnk[o]; be = bnk[256 + o];  m = bnk[512 + o];  v = bnk[768 + o]; }
            else              { int o = i - 512; g = bnv[o]; be = bnv[1024 + o]; m = bnv[2048 + o]; v = bnv[3072 + o]; }
            float s = g * rsqrtf(v + BN_EPS);
            float tt = be - m * s;
            // fold /scale (= *sqrt(kd)) AND log2(e) (exp2 softmax) into Q's affine
            if (i < 256) { s *= SQRT32 * LOG2E; tt *= SQRT32 * LOG2E; }
            s_qkv[i] = s; t_qkv[i] = tt;
        } else if (tid < 1536 + 384) {
            int o = tid - 1536;
            float g = bnp[o], be = bnp[384 + o], m = bnp[768 + o], v = bnp[1152 + o];
            float s = g * rsqrtf(v + BN_EPS);
            s_p[o] = s; t_p[o] = be - m * s;
        }
    }
}

// ---------------------------------------------------------------- gemm_qkv
// m97-style staging (BK=64, linear LDS, global_load_lds w/ pre-swizzled src,
// swizzled ds_read_b128). VECTORIZED EPILOGUES: MFMA operand roles chosen per
// path so each lane's 4 acc values (lq*4+r rows) are CONSECUTIVE in the output
// layout -> f16x4 stores (4x fewer store instrs than scalar).
// bx<4 (Q/K): A=w (rows o), B=x (cols n) -> D[o][n]; o consecutive per lane.
// bx>=4 (V):  A=x (rows n), B=wv (cols o) -> D[n][o]; n consecutive -> PV-
// permuted f16x4 into vbuf.
__global__ __launch_bounds__(256, 2) void gemm_qkv(
    const _Float16* __restrict__ wqk_h, const _Float16* __restrict__ wqk_l,
    const _Float16* __restrict__ wv_h,
    const _Float16* __restrict__ xT_hi, const _Float16* __restrict__ xT_lo,
    const float* __restrict__ S, const float* __restrict__ T,
    _Float16* __restrict__ qT_h, _Float16* __restrict__ qT_l,
    _Float16* __restrict__ kT_h, _Float16* __restrict__ kT_l,
    _Float16* __restrict__ vbuf)
{
    __shared__ __align__(16) _Float16 As_h[128 * 64];   // 16 KB each
    __shared__ __align__(16) _Float16 As_l[128 * 64];
    __shared__ __align__(16) _Float16 Bs_h[128 * 64];
    __shared__ __align__(16) _Float16 Bs_l[128 * 64];
    const int t = threadIdx.x, lane = t & 63, w = t >> 6;
    const int wr = w >> 1, wc = w & 1, l16 = lane & 15, lq = lane >> 4;
    const int bx = blockIdx.x, n0 = blockIdx.y * 128, b = blockIdx.z;
    const bool isv = bx >= 4;
    const int o0 = isv ? (bx - 4) * 128 : bx * 128;
    const _Float16* __restrict__ Ah = isv ? wv_h : wqk_h;

    f32x4 acc[4][4] = {};

    for (int kb = 0; kb < 384; kb += 64) {
        __syncthreads();
        // stage via global_load_lds: LDS[row][s] = global[row][s^(row&7)]
        #pragma unroll
        for (int p = 0; p < 4; p++) {
            int g = t + p * 256, row = g >> 3, s = g & 7;
            int col = ((s ^ (row & 7)) * 8);
            __builtin_amdgcn_global_load_lds(
                (gas_p)(const void*)(Ah + (size_t)(o0 + row) * 384 + kb + col),
                (las_p)(void*)&As_h[(p * 256 + w * 64) * 8], 16, 0, 0);
        }
        #pragma unroll
        for (int p = 0; p < 4; p++) {
            int g = t + p * 256, row = g >> 3, s = g & 7;
            int col = ((s ^ (row & 7)) * 8);
            __builtin_amdgcn_global_load_lds(
                (gas_p)(const void*)(xT_hi + ((size_t)(b * 1024) + n0 + row) * 384 + kb + col),
                (las_p)(void*)&Bs_h[(p * 256 + w * 64) * 8], 16, 0, 0);
        }
        if (!isv) {
            #pragma unroll
            for (int p = 0; p < 4; p++) {
                int g = t + p * 256, row = g >> 3, s = g & 7;
                int col = ((s ^ (row & 7)) * 8);
                __builtin_amdgcn_global_load_lds(
                    (gas_p)(const void*)(wqk_l + (size_t)(o0 + row) * 384 + kb + col),
                    (las_p)(void*)&As_l[(p * 256 + w * 64) * 8], 16, 0, 0);
            }
            #pragma unroll
            for (int p = 0; p < 4; p++) {
                int g = t + p * 256, row = g >> 3, s = g & 7;
                int col = ((s ^ (row & 7)) * 8);
                __builtin_amdgcn_global_load_lds(
                    (gas_p)(const void*)(xT_lo + ((size_t)(b * 1024) + n0 + row) * 384 + kb + col),
                    (las_p)(void*)&Bs_l[(p * 256 + w * 64) * 8], 16, 0, 0);
            }
        }
        __syncthreads();   // drains DMA (vmcnt 0) + joins waves

        if (!isv) {
            // A = w tiles (o rows), B = x tiles (n cols) -> D[o][n]
            #pragma unroll
            for (int kk = 0; kk < 2; kk++) {
                const int sl = ((kk * 4 + lq) ^ (l16 & 7)) * 8;
                f16x8 awh[4], awl[4], bxh[4], bxl[4];
                #pragma unroll
                for (int i = 0; i < 4; i++) {
                    int row = wr * 64 + i * 16 + l16;
                    awh[i] = *(const f16x8*)(&As_h[row * 64 + sl]);
                    awl[i] = *(const f16x8*)(&As_l[row * 64 + sl]);
                }
                #pragma unroll
                for (int j = 0; j < 4; j++) {
                    int row = wc * 64 + j * 16 + l16;
                    bxh[j] = *(const f16x8*)(&Bs_h[row * 64 + sl]);
                    bxl[j] = *(const f16x8*)(&Bs_l[row * 64 + sl]);
                }
                #pragma unroll
                for (int i = 0; i < 4; i++)
                    #pragma unroll
                    for (int j = 0; j < 4; j++) {
                        // identical term order to before: h*h, x_l*w_h, x_h*w_l
                        acc[i][j] = __builtin_amdgcn_mfma_f32_16x16x32_f16(awh[i], bxh[j], acc[i][j], 0, 0, 0);
                        acc[i][j] = __builtin_amdgcn_mfma_f32_16x16x32_f16(awh[i], bxl[j], acc[i][j], 0, 0, 0);
                        acc[i][j] = __builtin_amdgcn_mfma_f32_16x16x32_f16(awl[i], bxh[j], acc[i][j], 0, 0, 0);
                    }
            }
        } else {
            // A = x tiles (n rows), B = wv tiles (o cols) -> D[n][o]
            #pragma unroll
            for (int kk = 0; kk < 2; kk++) {
                const int sl = ((kk * 4 + lq) ^ (l16 & 7)) * 8;
                f16x8 axh[4], bwv[4];
                #pragma unroll
                for (int i = 0; i < 4; i++)
                    axh[i] = *(const f16x8*)(&Bs_h[(wr * 64 + i * 16 + l16) * 64 + sl]);
                #pragma unroll
                for (int j = 0; j < 4; j++)
                    bwv[j] = *(const f16x8*)(&As_h[(wc * 64 + j * 16 + l16) * 64 + sl]);
                #pragma unroll
                for (int i = 0; i < 4; i++)
                    #pragma unroll
                    for (int j = 0; j < 4; j++)
                        acc[i][j] = __builtin_amdgcn_mfma_f32_16x16x32_f16(axh[i], bwv[j], acc[i][j], 0, 0, 0);
            }
        }
    }

    if (!isv) {
        // D[o][n]: lane holds o = o0+wr*64+i*16+lq*4+r (4 consecutive), n fixed.
        // Block is all-Q (o0<256) or all-K -- branch is block-uniform.
        #pragma unroll
        for (int i = 0; i < 4; i++) {
            int ob = o0 + wr * 64 + i * 16 + lq * 4;
            float4 sc4 = *(const float4*)(S + ob);
            float4 sh4 = *(const float4*)(T + ob);
            #pragma unroll
            for (int j = 0; j < 4; j++) {
                int n = n0 + wc * 64 + j * 16 + l16;
                f16x4 hv, lv;
                #pragma unroll
                for (int r = 0; r < 4; r++) {
                    float v = acc[i][j][r] * ((const float*)&sc4)[r] + ((const float*)&sh4)[r];
                    _Float16 hh = (_Float16)v;
                    hv[r] = hh; lv[r] = (_Float16)(v - (float)hh);
                }
                if (ob < 256) {
                    size_t idx = (((size_t)(b * 8) + (ob >> 5)) * 1024 + n) * 32 + (ob & 31);
                    *(f16x4*)(qT_h + idx) = hv;
                    *(f16x4*)(qT_l + idx) = lv;
                } else {
                    int oo = ob - 256;
                    int hd = oo >> 5, c = oo & 31;
                    int f = ((n >> 5) & 1) * 2 + (c >> 4);           // (sub, kh)
                    size_t idx = ((((size_t)(b * 8 + hd) * 16 + (n >> 6)) * 4 + f) * 64
                                  + ((c >> 3) & 1) * 32 + (n & 31)) * 8 + (c & 7);
                    *(f16x4*)(kT_h + idx) = hv;
                    *(f16x4*)(kT_l + idx) = lv;
                }
            }
        }
    } else {
        // D[n][o]: lane holds n = n0+wr*64+i*16+lq*4+r (4 consecutive), o fixed.
        // PV-fragment permutation: k=i*16+lq*4+r -> ep=i*16+(lq&1)*8+(lq>>1)*4+r
        // (consecutive in r) -> single f16x4 store.
        #pragma unroll
        for (int i = 0; i < 4; i++) {
            int epb = i * 16 + (lq & 1) * 8 + (lq >> 1) * 4;
            int nhi = n0 + wr * 64;                       // n & ~63
            #pragma unroll
            for (int j = 0; j < 4; j++) {
                int o = o0 + wc * 64 + j * 16 + l16;
                float sc = S[512 + o], sh = T[512 + o];
                f16x4 vv;
                #pragma unroll
                for (int r = 0; r < 4; r++)
                    vv[r] = (_Float16)(acc[i][j][r] * sc + sh);
                *(f16x4*)(vbuf + ((size_t)(b * 1024) + o) * 1024 + nhi + epb) = vv;
            }
        }
    }
}

// ---------------------------------------------------------------- attn
// (unchanged -- best verified ~107-109 us)
// Online-softmax flash attention with one-tile-deferred PV; V triple-buffered,
// K double-buffered via global_load_lds; defer-max THR=8.
__device__ __forceinline__ f32x16 qk6(f16x8 kh0, f16x8 kl0, f16x8 kh1, f16x8 kl1,
                                      f16x8 qh0, f16x8 ql0, f16x8 qh1, f16x8 ql1) {
    f32x16 c = {};
    c = __builtin_amdgcn_mfma_f32_32x32x16_f16(kh0, qh0, c, 0, 0, 0);
    c = __builtin_amdgcn_mfma_f32_32x32x16_f16(kl0, qh0, c, 0, 0, 0);
    c = __builtin_amdgcn_mfma_f32_32x32x16_f16(kh0, ql0, c, 0, 0, 0);
    c = __builtin_amdgcn_mfma_f32_32x32x16_f16(kh1, qh1, c, 0, 0, 0);
    c = __builtin_amdgcn_mfma_f32_32x32x16_f16(kl1, qh1, c, 0, 0, 0);
    c = __builtin_amdgcn_mfma_f32_32x32x16_f16(kh1, ql1, c, 0, 0, 0);
    return c;
}

__global__ __launch_bounds__(256, 2) void attn(
    const _Float16* __restrict__ qT_h, const _Float16* __restrict__ qT_l,
    const _Float16* __restrict__ kT_h, const _Float16* __restrict__ kT_l,
    const _Float16* __restrict__ vbuf,
    _Float16* __restrict__ xxT_h, _Float16* __restrict__ xxT_l)
{
    __shared__ __align__(16) _Float16 Vs[3][128 * 64];   // 48 KB (triple)
    __shared__ __align__(16) _Float16 Ksh[2][2048];      // 8 KB
    __shared__ __align__(16) _Float16 Ksl[2][2048];      // 8 KB
    const int t = threadIdx.x, lane = t & 63, w = t >> 6;
    const int L = lane & 31, hl = lane >> 5;
    const int bh = blockIdx.x, qt = blockIdx.y;
    const int b = bh >> 3, h = bh & 7;
    const size_t vbase = ((size_t)(b * 1024) + h * 128) * 1024;

    // Q B-frags (hi/lo planes); once per block
    f16x8 bq_h[2], bq_l[2];
    {
        int q = qt * 128 + w * 32 + L;
        #pragma unroll
        for (int kh = 0; kh < 2; kh++) {
            size_t base = ((size_t)(bh * 1024) + q) * 32 + kh * 16 + hl * 8;
            bq_h[kh] = *(const f16x8*)(qT_h + base);
            bq_l[kh] = *(const f16x8*)(qT_l + base);
        }
    }

    f32x16 o_acc[4] = {};
    float m_st = -INFINITY, l_st = 0.f;
    f16x8 pf[4];        // P(kt-1), consumed one iteration later

    #define DMA_TILE(vb, kb, kt_)                                                  \
        {                                                                          \
            size_t ktb = (size_t)(bh * 16 + (kt_)) * 2048 + (size_t)t * 8;         \
            __builtin_amdgcn_global_load_lds((gas_p)(const void*)(kT_h + ktb),     \
                                             (las_p)(void*)&Ksh[kb][w * 512], 16, 0, 0); \
            __builtin_amdgcn_global_load_lds((gas_p)(const void*)(kT_l + ktb),     \
                                             (las_p)(void*)&Ksl[kb][w * 512], 16, 0, 0); \
            _Pragma("unroll")                                                      \
            for (int p = 0; p < 4; p++) {                                          \
                int g2 = t + p * 256;                                              \
                int d = g2 >> 3;                                                   \
                int kcg = (g2 & 7) ^ (d & 7);                                      \
                const _Float16* src = vbuf + vbase + (size_t)d * 1024              \
                                      + (kt_) * 64 + kcg * 8;                      \
                _Float16* dst = &Vs[vb][(p * 256 + w * 64) * 8];                   \
                __builtin_amdgcn_global_load_lds((gas_p)(const void*)src,          \
                                                 (las_p)(void*)dst, 16, 0, 0);     \
            }                                                                      \
        }

    DMA_TILE(0, 0, 0)
    __syncthreads();

    for (int kt = 0; kt < 16; kt++) {
        const int kcur = kt & 1;
        const int vprv = (kt + 2) % 3;       // buffer holding tile kt-1

        if (kt < 15) DMA_TILE((kt + 1) % 3, kcur ^ 1, kt + 1)

        // K frags from LDS (lgkmcnt only -- DMA stays in flight)
        const _Float16* khp = &Ksh[kcur][lane * 8];
        const _Float16* klp = &Ksl[kcur][lane * 8];
        f16x8 K0h = *(const f16x8*)(khp);
        f16x8 K1h = *(const f16x8*)(khp + 512);
        f16x8 K2h = *(const f16x8*)(khp + 1024);
        f16x8 K3h = *(const f16x8*)(khp + 1536);
        f16x8 K0l = *(const f16x8*)(klp);
        f16x8 K1l = *(const f16x8*)(klp + 512);
        f16x8 K2l = *(const f16x8*)(klp + 1024);
        f16x8 K3l = *(const f16x8*)(klp + 1536);

        __builtin_amdgcn_s_setprio(1);
        f32x16 c0 = qk6(K0h, K0l, K1h, K1l, bq_h[0], bq_l[0], bq_h[1], bq_l[1]);
        f32x16 c1 = qk6(K2h, K2l, K3h, K3l, bq_h[0], bq_l[0], bq_h[1], bq_l[1]);
        __builtin_amdgcn_s_setprio(0);

        // ---- PV(kt-1): independent of c0/c1, fills QK's latency shadow ----
        if (kt) {
            __builtin_amdgcn_s_setprio(1);
            #pragma unroll
            for (int s = 0; s < 4; s++) {
                int cp = (2 * s + hl) ^ (L & 7);
                #pragma unroll
                for (int dt = 0; dt < 4; dt++) {
                    f16x8 avp = *(const f16x8*)(&Vs[vprv][(dt * 32 + L) * 64 + cp * 8]);
                    o_acc[dt] = __builtin_amdgcn_mfma_f32_32x32x16_f16(avp, pf[s], o_acc[dt], 0, 0, 0);
                }
            }
            __builtin_amdgcn_s_setprio(0);
        }

        // ---- softmax(kt): overlaps PV's MFMA execution ----
        // row-max via max3 fusion (fmaxf(fmaxf(a,b),c) -> v_max3_f32)
        #define EL(e) ((e) < 16 ? c0[e] : c1[(e) - 16])
        float t1[11];
        #pragma unroll
        for (int g = 0; g < 10; g++)
            t1[g] = fmaxf(fmaxf(EL(3 * g), EL(3 * g + 1)), EL(3 * g + 2));
        t1[10] = fmaxf(EL(30), EL(31));
        #undef EL
        float t2a = fmaxf(fmaxf(t1[0], t1[1]), t1[2]);
        float t2b = fmaxf(fmaxf(t1[3], t1[4]), t1[5]);
        float t2c = fmaxf(fmaxf(t1[6], t1[7]), t1[8]);
        float t2d = fmaxf(t1[9], t1[10]);
        float mx0 = fmaxf(fmaxf(t2a, t2b), fmaxf(t2c, t2d));
        float mx = fmaxf(mx0, __shfl_xor(mx0, 32, 64));

        // defer-max: only rescale when the row max grows by > 8 (p <= 2^8 in f16)
        if (__any(mx > m_st + 8.f)) {
            float mnew = fmaxf(m_st, mx);
            float a = exp2f(m_st - mnew);
            l_st *= a;
            #pragma unroll
            for (int dt = 0; dt < 4; dt++)
                #pragma unroll
                for (int i = 0; i < 16; i++) o_acc[dt][i] *= a;
            m_st = mnew;
        }

        // exp -> packed f16 (cvt_pkrtz), partial-sum trees; store into pf for
        // consumption NEXT iteration
        float rs = 0.f;
        #pragma unroll
        for (int s = 0; s < 4; s++) {
            float pv[8];
            #pragma unroll
            for (int j = 0; j < 8; j++) {
                float cv = (s < 2) ? c0[(s & 1) * 8 + j] : c1[(s & 1) * 8 + j];
                pv[j] = exp2f(cv - m_st);
            }
            rs += ((pv[0] + pv[1]) + (pv[2] + pv[3])) + ((pv[4] + pv[5]) + (pv[6] + pv[7]));
            union { f16x8 v; h16x2 hh[4]; } u;
            #pragma unroll
            for (int j = 0; j < 4; j++)
                u.hh[j] = __builtin_amdgcn_cvt_pkrtz(pv[2 * j], pv[2 * j + 1]);
            pf[s] = u.v;
        }
        l_st += rs;

        if (kt < 15) __syncthreads();   // drains this iter's DMA + joins waves
    }
    #undef DMA_TILE

    // epilogue PV(15): tile 15 lives in Vs[15 % 3 == 0]
    {
        __builtin_amdgcn_s_setprio(1);
        #pragma unroll
        for (int s = 0; s < 4; s++) {
            int cp = (2 * s + hl) ^ (L & 7);
            #pragma unroll
            for (int dt = 0; dt < 4; dt++) {
                f16x8 avp = *(const f16x8*)(&Vs[0][(dt * 32 + L) * 64 + cp * 8]);
                o_acc[dt] = __builtin_amdgcn_mfma_f32_32x32x16_f16(avp, pf[s], o_acc[dt], 0, 0, 0);
            }
        }
        __builtin_amdgcn_s_setprio(0);
    }

    l_st += __shfl_xor(l_st, 32, 64);

    // epilogue: normalize, split hi/lo, store xxT[b][n=q][d]
    {
        float rl = 1.f / l_st;
        int q = qt * 128 + w * 32 + L;
        #pragma unroll
        for (int dt = 0; dt < 4; dt++) {
            #pragma unroll
            for (int gg = 0; gg < 4; gg++) {
                f16x4 hv, lv;
                #pragma unroll
                for (int rr = 0; rr < 4; rr++) {
                    float v = o_acc[dt][gg * 4 + rr] * rl;
                    _Float16 hh = (_Float16)v;
                    hv[rr] = hh; lv[rr] = (_Float16)(v - (float)hh);
                }
                size_t o = ((size_t)(b * 1024) + q) * 1024 + h * 128 + dt * 32 + gg * 8 + hl * 4;
                *(f16x4*)(xxT_h + o) = hv;
                *(f16x4*)(xxT_l + o) = lv;
            }
        }
    }
}

// ---------------------------------------------------------------- gemm_out
// m97-style staging + VECTORIZED EPILOGUE: A = xx (rows n), B = wp (cols o)
// -> D[n][o]; lane's 4 acc values are consecutive n -> float4 stores.
__global__ __launch_bounds__(256, 2) void gemm_out(
    const _Float16* __restrict__ wp_h,
    const _Float16* __restrict__ xxT_h, const _Float16* __restrict__ xxT_l,
    const float* __restrict__ S, const float* __restrict__ T,
    float* __restrict__ out)
{
    __shared__ __align__(16) _Float16 As[128 * 64];   // 16 KB (wp, rows o)
    __shared__ __align__(16) _Float16 Bh[64 * 64];    // 8 KB (xx hi, rows n)
    __shared__ __align__(16) _Float16 Bl[64 * 64];    // 8 KB (xx lo)
    const int t = threadIdx.x, lane = t & 63, w = t >> 6;
    const int wr = w >> 1, wc = w & 1, l16 = lane & 15, lq = lane >> 4;
    const int o0 = blockIdx.x * 128, n0 = blockIdx.y * 64, b = blockIdx.z;

    f32x4 acc[2][4] = {};   // [i: n-subtile][j: o-subtile]

    for (int kb = 0; kb < 1024; kb += 64) {
        __syncthreads();
        #pragma unroll
        for (int p = 0; p < 4; p++) {
            int g = t + p * 256, row = g >> 3, s = g & 7;
            int col = ((s ^ (row & 7)) * 8);
            __builtin_amdgcn_global_load_lds(
                (gas_p)(const void*)(wp_h + (size_t)(o0 + row) * 1024 + kb + col),
                (las_p)(void*)&As[(p * 256 + w * 64) * 8], 16, 0, 0);
        }
        #pragma unroll
        for (int p = 0; p < 2; p++) {
            int g = t + p * 256, row = g >> 3, s = g & 7;
            int col = ((s ^ (row & 7)) * 8);
            size_t src = ((size_t)(b * 1024) + n0 + row) * 1024 + kb + col;
            __builtin_amdgcn_global_load_lds(
                (gas_p)(const void*)(xxT_h + src),
                (las_p)(void*)&Bh[(p * 256 + w * 64) * 8], 16, 0, 0);
            __builtin_amdgcn_global_load_lds(
                (gas_p)(const void*)(xxT_l + src),
                (las_p)(void*)&Bl[(p * 256 + w * 64) * 8], 16, 0, 0);
        }
        __syncthreads();

        #pragma unroll
        for (int kk = 0; kk < 2; kk++) {
            const int sl = ((kk * 4 + lq) ^ (l16 & 7)) * 8;
            f16x8 axh[2], axl[2], bw[4];
            #pragma unroll
            for (int i = 0; i < 2; i++) {
                int row = wc * 32 + i * 16 + l16;
                axh[i] = *(const f16x8*)(&Bh[row * 64 + sl]);
                axl[i] = *(const f16x8*)(&Bl[row * 64 + sl]);
            }
            #pragma unroll
            for (int j = 0; j < 4; j++)
                bw[j] = *(const f16x8*)(&As[(wr * 64 + j * 16 + l16) * 64 + sl]);
            #pragma unroll
            for (int i = 0; i < 2; i++)
                #pragma unroll
                for (int j = 0; j < 4; j++) {
                    acc[i][j] = __builtin_amdgcn_mfma_f32_16x16x32_f16(axh[i], bw[j], acc[i][j], 0, 0, 0);
                    acc[i][j] = __builtin_amdgcn_mfma_f32_16x16x32_f16(axl[i], bw[j], acc[i][j], 0, 0, 0);
                }
        }
    }

    // D[n][o]: n = n0+wc*32+i*16+lq*4+r (consecutive), o = o0+wr*64+j*16+l16.
    #pragma unroll
    for (int i = 0; i < 2; i++) {
        int nb = n0 + wc * 32 + i * 16 + lq * 4;
        #pragma unroll
        for (int j = 0; j < 4; j++) {
            int o = o0 + wr * 64 + j * 16 + l16;
            float sc = S[o], sh = T[o];
            float4 vv;
            vv.x = acc[i][j][0] * sc + sh;
            vv.y = acc[i][j][1] * sc + sh;
            vv.z = acc[i][j][2] * sc + sh;
            vv.w = acc[i][j][3] * sc + sh;
            *(float4*)(out + ((size_t)(b * 384) + o) * 1024 + nb) = vv;
        }
    }
}

// ---------------------------------------------------------------- launch

extern "C" void kernel_launch(void* const* d_in, const int* in_sizes, int n_in,
                              void* d_out, int out_size, void* d_ws, size_t ws_size,
                              hipStream_t stream) {
    const float* x   = (const float*)d_in[0];
    const float* wq  = (const float*)d_in[1];
    const float* bnq = (const float*)d_in[2];
    const float* wk  = (const float*)d_in[3];
    const float* bnk = (const float*)d_in[4];
    const float* wv  = (const float*)d_in[5];
    const float* bnv = (const float*)d_in[6];
    const float* wp  = (const float*)d_in[7];
    const float* bnp = (const float*)d_in[8];
    float* out = (float*)d_out;
    (void)in_sizes; (void)n_in; (void)out_size; (void)ws_size;

    char* ws = (char*)d_ws;
    size_t off = 0;
    auto alloc = [&](size_t bytes) {
        void* p = ws + off;
        off = (off + bytes + 255) & ~(size_t)255;
        return p;
    };
    // --- region A: dead after gemm_qkv; reused as xxT_h (needs >= 33.56 MB) ---
    _Float16* xT_hi = (_Float16*)alloc((size_t)16 * 1024 * 384 * 2);   // 12.58 MB
    _Float16* xT_lo = (_Float16*)alloc((size_t)16 * 1024 * 384 * 2);   // 12.58 MB
    _Float16* wqk_h = (_Float16*)alloc((size_t)512 * 384 * 2);
    _Float16* wqk_l = (_Float16*)alloc((size_t)512 * 384 * 2);
    _Float16* wv_h  = (_Float16*)alloc((size_t)1024 * 384 * 2);
    alloc((size_t)7 * 1024 * 1024);                                     // pad region A to > 33.56 MB
    _Float16* xxT_h = (_Float16*)d_ws;                                  // alias over region A
    // --- live buffers ---
    _Float16* wp_h  = (_Float16*)alloc((size_t)384 * 1024 * 2);
    float*    s_qkv = (float*)alloc(1536 * 4);
    float*    t_qkv = (float*)alloc(1536 * 4);
    float*    s_p   = (float*)alloc(384 * 4);
    float*    t_p   = (float*)alloc(384 * 4);
    _Float16* qT_h  = (_Float16*)alloc((size_t)16 * 8 * 1024 * 32 * 2); // 8.39 MB
    _Float16* qT_l  = (_Float16*)alloc((size_t)16 * 8 * 1024 * 32 * 2); // 8.39 MB
    _Float16* kT_h  = (_Float16*)alloc((size_t)16 * 8 * 1024 * 32 * 2); // 8.39 MB
    _Float16* kT_l  = (_Float16*)alloc((size_t)16 * 8 * 1024 * 32 * 2); // 8.39 MB
    _Float16* vbuf  = (_Float16*)alloc((size_t)16 * 1024 * 1024 * 2);   // 33.55 MB
    _Float16* xxT_l = (_Float16*)alloc((size_t)16 * 1024 * 1024 * 2);   // 33.55 MB

    prep<<<dim3(6, 16, 17), dim3(256), 0, stream>>>(
        x, wq, wk, wv, wp, bnq, bnk, bnv, bnp,
        xT_hi, xT_lo, wqk_h, wqk_l, wv_h, wp_h, s_qkv, t_qkv, s_p, t_p);

    gemm_qkv<<<dim3(12, 8, 16), dim3(256), 0, stream>>>(
        wqk_h, wqk_l, wv_h, xT_hi, xT_lo, s_qkv, t_qkv,
        qT_h, qT_l, kT_h, kT_l, vbuf);

    attn<<<dim3(128, 8), dim3(256), 0, stream>>>(qT_h, qT_l, kT_h, kT_l, vbuf, xxT_h, xxT_l);

    gemm_out<<<dim3(3, 16, 16), dim3(256), 0, stream>>>(wp_h, xxT_h, xxT_l, s_p, t_p, out);
}

// Round 12
// 281.850 us; speedup vs baseline: 1.1032x; 1.0059x over previous
//
#include <hip/hip_runtime.h>

typedef _Float16 f16x8 __attribute__((ext_vector_type(8)));
typedef _Float16 f16x4 __attribute__((ext_vector_type(4)));
typedef __fp16 h16x2 __attribute__((ext_vector_type(2)));
typedef float f32x4 __attribute__((ext_vector_type(4)));
typedef float f32x16 __attribute__((ext_vector_type(16)));

#define BN_EPS 1e-5f
#define SQRT32 5.656854249492381f
#define LOG2E  1.4426950408889634f

typedef const __attribute__((address_space(1))) void* gas_p;
typedef __attribute__((address_space(3))) void* las_p;

// ---------------------------------------------------------------- prep (merged)
// z<16: x [b][c=384][n] fp32 -> xT_hi/lo [b][n][c] fp16 planes (transpose+split).
// z==16: weight conversion + BN affine fold.
__global__ __launch_bounds__(256) void prep(
    const float* __restrict__ x,
    const float* __restrict__ wq, const float* __restrict__ wk,
    const float* __restrict__ wv, const float* __restrict__ wp,
    const float* __restrict__ bnq, const float* __restrict__ bnk,
    const float* __restrict__ bnv, const float* __restrict__ bnp,
    _Float16* __restrict__ xT_hi, _Float16* __restrict__ xT_lo,
    _Float16* __restrict__ wqk_h, _Float16* __restrict__ wqk_l,
    _Float16* __restrict__ wv_h,  _Float16* __restrict__ wp_h,
    float* __restrict__ s_qkv, float* __restrict__ t_qkv,
    float* __restrict__ s_p,   float* __restrict__ t_p)
{
    __shared__ float Tx[64][65];
    const int t = threadIdx.x;
    if (blockIdx.z < 16) {
        const int ct = blockIdx.x, nt = blockIdx.y, b = blockIdx.z;
        const int c0 = ct * 64, n0 = nt * 64;
        {
            int tr = t >> 4, tc = (t & 15) * 4;
            #pragma unroll
            for (int p = 0; p < 4; p++) {
                int r = tr + p * 16;
                float4 v = *(const float4*)(x + ((size_t)(b * 384 + c0 + r)) * 1024 + n0 + tc);
                Tx[r][tc + 0] = v.x; Tx[r][tc + 1] = v.y; Tx[r][tc + 2] = v.z; Tx[r][tc + 3] = v.w;
            }
        }
        __syncthreads();
        {
            int nn = t >> 2, cc = (t & 3) * 16;
            f16x8 h0, h1, l0, l1;
            #pragma unroll
            for (int i = 0; i < 8; i++) {
                float v = Tx[cc + i][nn];
                _Float16 hh = (_Float16)v;
                h0[i] = hh; l0[i] = (_Float16)(v - (float)hh);
            }
            #pragma unroll
            for (int i = 0; i < 8; i++) {
                float v = Tx[cc + 8 + i][nn];
                _Float16 hh = (_Float16)v;
                h1[i] = hh; l1[i] = (_Float16)(v - (float)hh);
            }
            size_t o = ((size_t)(b * 1024 + n0 + nn)) * 384 + c0 + cc;
            *(f16x8*)(xT_hi + o) = h0; *(f16x8*)(xT_hi + o + 8) = h1;
            *(f16x8*)(xT_lo + o) = l0; *(f16x8*)(xT_lo + o + 8) = l1;
        }
    } else {
        const int NQK = 512 * 384, NV = 1024 * 384, NP = 384 * 1024;
        int tid = (blockIdx.y * 6 + blockIdx.x) * 256 + t;       // 0..24575
        for (int i = tid; i < NQK + NV + NP; i += 24576) {
            if (i < NQK) {
                int o = i / 384, c = i - o * 384;
                float v = (o < 256) ? wq[o * 384 + c] : wk[(o - 256) * 384 + c];
                _Float16 hh = (_Float16)v;
                wqk_h[i] = hh; wqk_l[i] = (_Float16)(v - (float)hh);
            } else if (i < NQK + NV) {
                wv_h[i - NQK] = (_Float16)wv[i - NQK];
            } else {
                wp_h[i - NQK - NV] = (_Float16)wp[i - NQK - NV];
            }
        }
        if (tid < 1536) {
            int i = tid;
            float g, be, m, v;
            if (i < 256)      { int o = i;       g = bnq[o]; be = bnq[256 + o];  m = bnq[512 + o];  v = bnq[768 + o]; }
            else if (i < 512) { int o = i - 256; g = bnk[o]; be = bnk[256 + o];  m = bnk[512 + o];  v = bnk[768 + o]; }
            else              { int o = i - 512; g = bnv[o]; be = bnv[1024 + o]; m = bnv[2048 + o]; v = bnv[3072 + o]; }
            float s = g * rsqrtf(v + BN_EPS);
            float tt = be - m * s;
            // fold /scale (= *sqrt(kd)) AND log2(e) (exp2 softmax) into Q's affine
            if (i < 256) { s *= SQRT32 * LOG2E; tt *= SQRT32 * LOG2E; }
            s_qkv[i] = s; t_qkv[i] = tt;
        } else if (tid < 1536 + 384) {
            int o = tid - 1536;
            float g = bnp[o], be = bnp[384 + o], m = bnp[768 + o], v = bnp[1152 + o];
            float s = g * rsqrtf(v + BN_EPS);
            s_p[o] = s; t_p[o] = be - m * s;
        }
    }
}

// ---------------------------------------------------------------- gemm_qkv
// m97-style staging (BK=64, linear LDS, global_load_lds w/ pre-swizzled src,
// swizzled ds_read_b128). VECTORIZED EPILOGUES: MFMA operand roles chosen per
// path so each lane's 4 acc values (lq*4+r rows) are CONSECUTIVE in the output
// layout -> f16x4 stores (4x fewer store instrs than scalar).
// bx<4 (Q/K): A=w (rows o), B=x (cols n) -> D[o][n]; o consecutive per lane.
// bx>=4 (V):  A=x (rows n), B=wv (cols o) -> D[n][o]; n consecutive -> PV-
// permuted f16x4 into vbuf.
__global__ __launch_bounds__(256, 2) void gemm_qkv(
    const _Float16* __restrict__ wqk_h, const _Float16* __restrict__ wqk_l,
    const _Float16* __restrict__ wv_h,
    const _Float16* __restrict__ xT_hi, const _Float16* __restrict__ xT_lo,
    const float* __restrict__ S, const float* __restrict__ T,
    _Float16* __restrict__ qT_h, _Float16* __restrict__ qT_l,
    _Float16* __restrict__ kT_h, _Float16* __restrict__ kT_l,
    _Float16* __restrict__ vbuf)
{
    __shared__ __align__(16) _Float16 As_h[128 * 64];   // 16 KB each
    __shared__ __align__(16) _Float16 As_l[128 * 64];
    __shared__ __align__(16) _Float16 Bs_h[128 * 64];
    __shared__ __align__(16) _Float16 Bs_l[128 * 64];
    const int t = threadIdx.x, lane = t & 63, w = t >> 6;
    const int wr = w >> 1, wc = w & 1, l16 = lane & 15, lq = lane >> 4;
    const int bx = blockIdx.x, n0 = blockIdx.y * 128, b = blockIdx.z;
    const bool isv = bx >= 4;
    const int o0 = isv ? (bx - 4) * 128 : bx * 128;
    const _Float16* __restrict__ Ah = isv ? wv_h : wqk_h;

    f32x4 acc[4][4] = {};

    for (int kb = 0; kb < 384; kb += 64) {
        __syncthreads();
        // stage via global_load_lds: LDS[row][s] = global[row][s^(row&7)]
        #pragma unroll
        for (int p = 0; p < 4; p++) {
            int g = t + p * 256, row = g >> 3, s = g & 7;
            int col = ((s ^ (row & 7)) * 8);
            __builtin_amdgcn_global_load_lds(
                (gas_p)(const void*)(Ah + (size_t)(o0 + row) * 384 + kb + col),
                (las_p)(void*)&As_h[(p * 256 + w * 64) * 8], 16, 0, 0);
        }
        #pragma unroll
        for (int p = 0; p < 4; p++) {
            int g = t + p * 256, row = g >> 3, s = g & 7;
            int col = ((s ^ (row & 7)) * 8);
            __builtin_amdgcn_global_load_lds(
                (gas_p)(const void*)(xT_hi + ((size_t)(b * 1024) + n0 + row) * 384 + kb + col),
                (las_p)(void*)&Bs_h[(p * 256 + w * 64) * 8], 16, 0, 0);
        }
        if (!isv) {
            #pragma unroll
            for (int p = 0; p < 4; p++) {
                int g = t + p * 256, row = g >> 3, s = g & 7;
                int col = ((s ^ (row & 7)) * 8);
                __builtin_amdgcn_global_load_lds(
                    (gas_p)(const void*)(wqk_l + (size_t)(o0 + row) * 384 + kb + col),
                    (las_p)(void*)&As_l[(p * 256 + w * 64) * 8], 16, 0, 0);
            }
            #pragma unroll
            for (int p = 0; p < 4; p++) {
                int g = t + p * 256, row = g >> 3, s = g & 7;
                int col = ((s ^ (row & 7)) * 8);
                __builtin_amdgcn_global_load_lds(
                    (gas_p)(const void*)(xT_lo + ((size_t)(b * 1024) + n0 + row) * 384 + kb + col),
                    (las_p)(void*)&Bs_l[(p * 256 + w * 64) * 8], 16, 0, 0);
            }
        }
        __syncthreads();   // drains DMA (vmcnt 0) + joins waves

        if (!isv) {
            // A = w tiles (o rows), B = x tiles (n cols) -> D[o][n]
            #pragma unroll
            for (int kk = 0; kk < 2; kk++) {
                const int sl = ((kk * 4 + lq) ^ (l16 & 7)) * 8;
                f16x8 awh[4], awl[4], bxh[4], bxl[4];
                #pragma unroll
                for (int i = 0; i < 4; i++) {
                    int row = wr * 64 + i * 16 + l16;
                    awh[i] = *(const f16x8*)(&As_h[row * 64 + sl]);
                    awl[i] = *(const f16x8*)(&As_l[row * 64 + sl]);
                }
                #pragma unroll
                for (int j = 0; j < 4; j++) {
                    int row = wc * 64 + j * 16 + l16;
                    bxh[j] = *(const f16x8*)(&Bs_h[row * 64 + sl]);
                    bxl[j] = *(const f16x8*)(&Bs_l[row * 64 + sl]);
                }
                #pragma unroll
                for (int i = 0; i < 4; i++)
                    #pragma unroll
                    for (int j = 0; j < 4; j++) {
                        // identical term order to before: h*h, x_l*w_h, x_h*w_l
                        acc[i][j] = __builtin_amdgcn_mfma_f32_16x16x32_f16(awh[i], bxh[j], acc[i][j], 0, 0, 0);
                        acc[i][j] = __builtin_amdgcn_mfma_f32_16x16x32_f16(awh[i], bxl[j], acc[i][j], 0, 0, 0);
                        acc[i][j] = __builtin_amdgcn_mfma_f32_16x16x32_f16(awl[i], bxh[j], acc[i][j], 0, 0, 0);
                    }
            }
        } else {
            // A = x tiles (n rows), B = wv tiles (o cols) -> D[n][o]
            #pragma unroll
            for (int kk = 0; kk < 2; kk++) {
                const int sl = ((kk * 4 + lq) ^ (l16 & 7)) * 8;
                f16x8 axh[4], bwv[4];
                #pragma unroll
                for (int i = 0; i < 4; i++)
                    axh[i] = *(const f16x8*)(&Bs_h[(wr * 64 + i * 16 + l16) * 64 + sl]);
                #pragma unroll
                for (int j = 0; j < 4; j++)
                    bwv[j] = *(const f16x8*)(&As_h[(wc * 64 + j * 16 + l16) * 64 + sl]);
                #pragma unroll
                for (int i = 0; i < 4; i++)
                    #pragma unroll
                    for (int j = 0; j < 4; j++)
                        acc[i][j] = __builtin_amdgcn_mfma_f32_16x16x32_f16(axh[i], bwv[j], acc[i][j], 0, 0, 0);
            }
        }
    }

    if (!isv) {
        // D[o][n]: lane holds o = o0+wr*64+i*16+lq*4+r (4 consecutive), n fixed.
        // Block is all-Q (o0<256) or all-K -- branch is block-uniform.
        #pragma unroll
        for (int i = 0; i < 4; i++) {
            int ob = o0 + wr * 64 + i * 16 + lq * 4;
            float4 sc4 = *(const float4*)(S + ob);
            float4 sh4 = *(const float4*)(T + ob);
            #pragma unroll
            for (int j = 0; j < 4; j++) {
                int n = n0 + wc * 64 + j * 16 + l16;
                f16x4 hv, lv;
                #pragma unroll
                for (int r = 0; r < 4; r++) {
                    float v = acc[i][j][r] * ((const float*)&sc4)[r] + ((const float*)&sh4)[r];
                    _Float16 hh = (_Float16)v;
                    hv[r] = hh; lv[r] = (_Float16)(v - (float)hh);
                }
                if (ob < 256) {
                    size_t idx = (((size_t)(b * 8) + (ob >> 5)) * 1024 + n) * 32 + (ob & 31);
                    *(f16x4*)(qT_h + idx) = hv;
                    *(f16x4*)(qT_l + idx) = lv;
                } else {
                    int oo = ob - 256;
                    int hd = oo >> 5, c = oo & 31;
                    int f = ((n >> 5) & 1) * 2 + (c >> 4);           // (sub, kh)
                    size_t idx = ((((size_t)(b * 8 + hd) * 16 + (n >> 6)) * 4 + f) * 64
                                  + ((c >> 3) & 1) * 32 + (n & 31)) * 8 + (c & 7);
                    *(f16x4*)(kT_h + idx) = hv;
                    *(f16x4*)(kT_l + idx) = lv;
                }
            }
        }
    } else {
        // D[n][o]: lane holds n = n0+wr*64+i*16+lq*4+r (4 consecutive), o fixed.
        // PV-fragment permutation: k=i*16+lq*4+r -> ep=i*16+(lq&1)*8+(lq>>1)*4+r
        // (consecutive in r) -> single f16x4 store.
        #pragma unroll
        for (int i = 0; i < 4; i++) {
            int epb = i * 16 + (lq & 1) * 8 + (lq >> 1) * 4;
            int nhi = n0 + wr * 64;                       // n & ~63
            #pragma unroll
            for (int j = 0; j < 4; j++) {
                int o = o0 + wc * 64 + j * 16 + l16;
                float sc = S[512 + o], sh = T[512 + o];
                f16x4 vv;
                #pragma unroll
                for (int r = 0; r < 4; r++)
                    vv[r] = (_Float16)(acc[i][j][r] * sc + sh);
                *(f16x4*)(vbuf + ((size_t)(b * 1024) + o) * 1024 + nhi + epb) = vv;
            }
        }
    }
}

// ---------------------------------------------------------------- attn
// (unchanged from round 8 -- verified pass at 283.5 us total)
// Online-softmax flash attention with one-tile-deferred PV; V triple-buffered,
// K double-buffered via global_load_lds; defer-max THR=8.
__device__ __forceinline__ f32x16 qk6(f16x8 kh0, f16x8 kl0, f16x8 kh1, f16x8 kl1,
                                      f16x8 qh0, f16x8 ql0, f16x8 qh1, f16x8 ql1) {
    f32x16 c = {};
    c = __builtin_amdgcn_mfma_f32_32x32x16_f16(kh0, qh0, c, 0, 0, 0);
    c = __builtin_amdgcn_mfma_f32_32x32x16_f16(kl0, qh0, c, 0, 0, 0);
    c = __builtin_amdgcn_mfma_f32_32x32x16_f16(kh0, ql0, c, 0, 0, 0);
    c = __builtin_amdgcn_mfma_f32_32x32x16_f16(kh1, qh1, c, 0, 0, 0);
    c = __builtin_amdgcn_mfma_f32_32x32x16_f16(kl1, qh1, c, 0, 0, 0);
    c = __builtin_amdgcn_mfma_f32_32x32x16_f16(kh1, ql1, c, 0, 0, 0);
    return c;
}

__global__ __launch_bounds__(256, 2) void attn(
    const _Float16* __restrict__ qT_h, const _Float16* __restrict__ qT_l,
    const _Float16* __restrict__ kT_h, const _Float16* __restrict__ kT_l,
    const _Float16* __restrict__ vbuf,
    _Float16* __restrict__ xxT_h, _Float16* __restrict__ xxT_l)
{
    __shared__ __align__(16) _Float16 Vs[3][128 * 64];   // 48 KB (triple)
    __shared__ __align__(16) _Float16 Ksh[2][2048];      // 8 KB
    __shared__ __align__(16) _Float16 Ksl[2][2048];      // 8 KB
    const int t = threadIdx.x, lane = t & 63, w = t >> 6;
    const int L = lane & 31, hl = lane >> 5;
    const int bh = blockIdx.x, qt = blockIdx.y;
    const int b = bh >> 3, h = bh & 7;
    const size_t vbase = ((size_t)(b * 1024) + h * 128) * 1024;

    // Q B-frags (hi/lo planes); once per block
    f16x8 bq_h[2], bq_l[2];
    {
        int q = qt * 128 + w * 32 + L;
        #pragma unroll
        for (int kh = 0; kh < 2; kh++) {
            size_t base = ((size_t)(bh * 1024) + q) * 32 + kh * 16 + hl * 8;
            bq_h[kh] = *(const f16x8*)(qT_h + base);
            bq_l[kh] = *(const f16x8*)(qT_l + base);
        }
    }

    f32x16 o_acc[4] = {};
    float m_st = -INFINITY, l_st = 0.f;
    f16x8 pf[4];        // P(kt-1), consumed one iteration later

    #define DMA_TILE(vb, kb, kt_)                                                  \
        {                                                                          \
            size_t ktb = (size_t)(bh * 16 + (kt_)) * 2048 + (size_t)t * 8;         \
            __builtin_amdgcn_global_load_lds((gas_p)(const void*)(kT_h + ktb),     \
                                             (las_p)(void*)&Ksh[kb][w * 512], 16, 0, 0); \
            __builtin_amdgcn_global_load_lds((gas_p)(const void*)(kT_l + ktb),     \
                                             (las_p)(void*)&Ksl[kb][w * 512], 16, 0, 0); \
            _Pragma("unroll")                                                      \
            for (int p = 0; p < 4; p++) {                                          \
                int g2 = t + p * 256;                                              \
                int d = g2 >> 3;                                                   \
                int kcg = (g2 & 7) ^ (d & 7);                                      \
                const _Float16* src = vbuf + vbase + (size_t)d * 1024              \
                                      + (kt_) * 64 + kcg * 8;                      \
                _Float16* dst = &Vs[vb][(p * 256 + w * 64) * 8];                   \
                __builtin_amdgcn_global_load_lds((gas_p)(const void*)src,          \
                                                 (las_p)(void*)dst, 16, 0, 0);     \
            }                                                                      \
        }

    DMA_TILE(0, 0, 0)
    __syncthreads();

    for (int kt = 0; kt < 16; kt++) {
        const int kcur = kt & 1;
        const int vprv = (kt + 2) % 3;       // buffer holding tile kt-1

        if (kt < 15) DMA_TILE((kt + 1) % 3, kcur ^ 1, kt + 1)

        // K frags from LDS (lgkmcnt only -- DMA stays in flight)
        const _Float16* khp = &Ksh[kcur][lane * 8];
        const _Float16* klp = &Ksl[kcur][lane * 8];
        f16x8 K0h = *(const f16x8*)(khp);
        f16x8 K1h = *(const f16x8*)(khp + 512);
        f16x8 K2h = *(const f16x8*)(khp + 1024);
        f16x8 K3h = *(const f16x8*)(khp + 1536);
        f16x8 K0l = *(const f16x8*)(klp);
        f16x8 K1l = *(const f16x8*)(klp + 512);
        f16x8 K2l = *(const f16x8*)(klp + 1024);
        f16x8 K3l = *(const f16x8*)(klp + 1536);

        __builtin_amdgcn_s_setprio(1);
        f32x16 c0 = qk6(K0h, K0l, K1h, K1l, bq_h[0], bq_l[0], bq_h[1], bq_l[1]);
        f32x16 c1 = qk6(K2h, K2l, K3h, K3l, bq_h[0], bq_l[0], bq_h[1], bq_l[1]);
        __builtin_amdgcn_s_setprio(0);

        // ---- PV(kt-1): independent of c0/c1, fills QK's latency shadow ----
        if (kt) {
            __builtin_amdgcn_s_setprio(1);
            #pragma unroll
            for (int s = 0; s < 4; s++) {
                int cp = (2 * s + hl) ^ (L & 7);
                #pragma unroll
                for (int dt = 0; dt < 4; dt++) {
                    f16x8 avp = *(const f16x8*)(&Vs[vprv][(dt * 32 + L) * 64 + cp * 8]);
                    o_acc[dt] = __builtin_amdgcn_mfma_f32_32x32x16_f16(avp, pf[s], o_acc[dt], 0, 0, 0);
                }
            }
            __builtin_amdgcn_s_setprio(0);
        }

        // ---- softmax(kt): overlaps PV's MFMA execution ----
        // row-max via max3 fusion (fmaxf(fmaxf(a,b),c) -> v_max3_f32)
        #define EL(e) ((e) < 16 ? c0[e] : c1[(e) - 16])
        float t1[11];
        #pragma unroll
        for (int g = 0; g < 10; g++)
            t1[g] = fmaxf(fmaxf(EL(3 * g), EL(3 * g + 1)), EL(3 * g + 2));
        t1[10] = fmaxf(EL(30), EL(31));
        #undef EL
        float t2a = fmaxf(fmaxf(t1[0], t1[1]), t1[2]);
        float t2b = fmaxf(fmaxf(t1[3], t1[4]), t1[5]);
        float t2c = fmaxf(fmaxf(t1[6], t1[7]), t1[8]);
        float t2d = fmaxf(t1[9], t1[10]);
        float mx0 = fmaxf(fmaxf(t2a, t2b), fmaxf(t2c, t2d));
        float mx = fmaxf(mx0, __shfl_xor(mx0, 32, 64));

        // defer-max: only rescale when the row max grows by > 8 (p <= 2^8 in f16)
        if (__any(mx > m_st + 8.f)) {
            float mnew = fmaxf(m_st, mx);
            float a = exp2f(m_st - mnew);
            l_st *= a;
            #pragma unroll
            for (int dt = 0; dt < 4; dt++)
                #pragma unroll
                for (int i = 0; i < 16; i++) o_acc[dt][i] *= a;
            m_st = mnew;
        }

        // exp -> packed f16 (cvt_pkrtz), partial-sum trees; store into pf for
        // consumption NEXT iteration
        float rs = 0.f;
        #pragma unroll
        for (int s = 0; s < 4; s++) {
            float pv[8];
            #pragma unroll
            for (int j = 0; j < 8; j++) {
                float cv = (s < 2) ? c0[(s & 1) * 8 + j] : c1[(s & 1) * 8 + j];
                pv[j] = exp2f(cv - m_st);
            }
            rs += ((pv[0] + pv[1]) + (pv[2] + pv[3])) + ((pv[4] + pv[5]) + (pv[6] + pv[7]));
            union { f16x8 v; h16x2 hh[4]; } u;
            #pragma unroll
            for (int j = 0; j < 4; j++)
                u.hh[j] = __builtin_amdgcn_cvt_pkrtz(pv[2 * j], pv[2 * j + 1]);
            pf[s] = u.v;
        }
        l_st += rs;

        if (kt < 15) __syncthreads();   // drains this iter's DMA + joins waves
    }
    #undef DMA_TILE

    // epilogue PV(15): tile 15 lives in Vs[15 % 3 == 0]
    {
        __builtin_amdgcn_s_setprio(1);
        #pragma unroll
        for (int s = 0; s < 4; s++) {
            int cp = (2 * s + hl) ^ (L & 7);
            #pragma unroll
            for (int dt = 0; dt < 4; dt++) {
                f16x8 avp = *(const f16x8*)(&Vs[0][(dt * 32 + L) * 64 + cp * 8]);
                o_acc[dt] = __builtin_amdgcn_mfma_f32_32x32x16_f16(avp, pf[s], o_acc[dt], 0, 0, 0);
            }
        }
        __builtin_amdgcn_s_setprio(0);
    }

    l_st += __shfl_xor(l_st, 32, 64);

    // epilogue: normalize, split hi/lo, store xxT[b][n=q][d]
    {
        float rl = 1.f / l_st;
        int q = qt * 128 + w * 32 + L;
        #pragma unroll
        for (int dt = 0; dt < 4; dt++) {
            #pragma unroll
            for (int gg = 0; gg < 4; gg++) {
                f16x4 hv, lv;
                #pragma unroll
                for (int rr = 0; rr < 4; rr++) {
                    float v = o_acc[dt][gg * 4 + rr] * rl;
                    _Float16 hh = (_Float16)v;
                    hv[rr] = hh; lv[rr] = (_Float16)(v - (float)hh);
                }
                size_t o = ((size_t)(b * 1024) + q) * 1024 + h * 128 + dt * 32 + gg * 8 + hl * 4;
                *(f16x4*)(xxT_h + o) = hv;
                *(f16x4*)(xxT_l + o) = lv;
            }
        }
    }
}

// ---------------------------------------------------------------- gemm_out
// ONLY change vs round 8: drop the xx-lo term (xx error is not exp-amplified;
// measured budget 2.0 vs threshold 7.04). 1-term f16, half B-staging.
// A = xx_hi (rows n), B = wp (cols o) -> D[n][o]; float4 stores.
__global__ __launch_bounds__(256, 2) void gemm_out(
    const _Float16* __restrict__ wp_h,
    const _Float16* __restrict__ xxT_h,
    const float* __restrict__ S, const float* __restrict__ T,
    float* __restrict__ out)
{
    __shared__ __align__(16) _Float16 As[128 * 64];   // 16 KB (wp, rows o)
    __shared__ __align__(16) _Float16 Bh[64 * 64];    // 8 KB (xx hi, rows n)
    const int t = threadIdx.x, lane = t & 63, w = t >> 6;
    const int wr = w >> 1, wc = w & 1, l16 = lane & 15, lq = lane >> 4;
    const int o0 = blockIdx.x * 128, n0 = blockIdx.y * 64, b = blockIdx.z;

    f32x4 acc[2][4] = {};   // [i: n-subtile][j: o-subtile]

    for (int kb = 0; kb < 1024; kb += 64) {
        __syncthreads();
        #pragma unroll
        for (int p = 0; p < 4; p++) {
            int g = t + p * 256, row = g >> 3, s = g & 7;
            int col = ((s ^ (row & 7)) * 8);
            __builtin_amdgcn_global_load_lds(
                (gas_p)(const void*)(wp_h + (size_t)(o0 + row) * 1024 + kb + col),
                (las_p)(void*)&As[(p * 256 + w * 64) * 8], 16, 0, 0);
        }
        #pragma unroll
        for (int p = 0; p < 2; p++) {
            int g = t + p * 256, row = g >> 3, s = g & 7;
            int col = ((s ^ (row & 7)) * 8);
            size_t src = ((size_t)(b * 1024) + n0 + row) * 1024 + kb + col;
            __builtin_amdgcn_global_load_lds(
                (gas_p)(const void*)(xxT_h + src),
                (las_p)(void*)&Bh[(p * 256 + w * 64) * 8], 16, 0, 0);
        }
        __syncthreads();

        #pragma unroll
        for (int kk = 0; kk < 2; kk++) {
            const int sl = ((kk * 4 + lq) ^ (l16 & 7)) * 8;
            f16x8 axh[2], bw[4];
            #pragma unroll
            for (int i = 0; i < 2; i++)
                axh[i] = *(const f16x8*)(&Bh[(wc * 32 + i * 16 + l16) * 64 + sl]);
            #pragma unroll
            for (int j = 0; j < 4; j++)
                bw[j] = *(const f16x8*)(&As[(wr * 64 + j * 16 + l16) * 64 + sl]);
            #pragma unroll
            for (int i = 0; i < 2; i++)
                #pragma unroll
                for (int j = 0; j < 4; j++)
                    acc[i][j] = __builtin_amdgcn_mfma_f32_16x16x32_f16(axh[i], bw[j], acc[i][j], 0, 0, 0);
        }
    }

    // D[n][o]: n = n0+wc*32+i*16+lq*4+r (consecutive), o = o0+wr*64+j*16+l16.
    #pragma unroll
    for (int i = 0; i < 2; i++) {
        int nb = n0 + wc * 32 + i * 16 + lq * 4;
        #pragma unroll
        for (int j = 0; j < 4; j++) {
            int o = o0 + wr * 64 + j * 16 + l16;
            float sc = S[o], sh = T[o];
            float4 vv;
            vv.x = acc[i][j][0] * sc + sh;
            vv.y = acc[i][j][1] * sc + sh;
            vv.z = acc[i][j][2] * sc + sh;
            vv.w = acc[i][j][3] * sc + sh;
            *(float4*)(out + ((size_t)(b * 384) + o) * 1024 + nb) = vv;
        }
    }
}

// ---------------------------------------------------------------- launch

extern "C" void kernel_launch(void* const* d_in, const int* in_sizes, int n_in,
                              void* d_out, int out_size, void* d_ws, size_t ws_size,
                              hipStream_t stream) {
    const float* x   = (const float*)d_in[0];
    const float* wq  = (const float*)d_in[1];
    const float* bnq = (const float*)d_in[2];
    const float* wk  = (const float*)d_in[3];
    const float* bnk = (const float*)d_in[4];
    const float* wv  = (const float*)d_in[5];
    const float* bnv = (const float*)d_in[6];
    const float* wp  = (const float*)d_in[7];
    const float* bnp = (const float*)d_in[8];
    float* out = (float*)d_out;
    (void)in_sizes; (void)n_in; (void)out_size; (void)ws_size;

    char* ws = (char*)d_ws;
    size_t off = 0;
    auto alloc = [&](size_t bytes) {
        void* p = ws + off;
        off = (off + bytes + 255) & ~(size_t)255;
        return p;
    };
    // --- region A: dead after gemm_qkv; reused as xxT_h (needs >= 33.56 MB) ---
    _Float16* xT_hi = (_Float16*)alloc((size_t)16 * 1024 * 384 * 2);   // 12.58 MB
    _Float16* xT_lo = (_Float16*)alloc((size_t)16 * 1024 * 384 * 2);   // 12.58 MB
    _Float16* wqk_h = (_Float16*)alloc((size_t)512 * 384 * 2);
    _Float16* wqk_l = (_Float16*)alloc((size_t)512 * 384 * 2);
    _Float16* wv_h  = (_Float16*)alloc((size_t)1024 * 384 * 2);
    alloc((size_t)7 * 1024 * 1024);                                     // pad region A to > 33.56 MB
    _Float16* xxT_h = (_Float16*)d_ws;                                  // alias over region A
    // --- live buffers ---
    _Float16* wp_h  = (_Float16*)alloc((size_t)384 * 1024 * 2);
    float*    s_qkv = (float*)alloc(1536 * 4);
    float*    t_qkv = (float*)alloc(1536 * 4);
    float*    s_p   = (float*)alloc(384 * 4);
    float*    t_p   = (float*)alloc(384 * 4);
    _Float16* qT_h  = (_Float16*)alloc((size_t)16 * 8 * 1024 * 32 * 2); // 8.39 MB
    _Float16* qT_l  = (_Float16*)alloc((size_t)16 * 8 * 1024 * 32 * 2); // 8.39 MB
    _Float16* kT_h  = (_Float16*)alloc((size_t)16 * 8 * 1024 * 32 * 2); // 8.39 MB
    _Float16* kT_l  = (_Float16*)alloc((size_t)16 * 8 * 1024 * 32 * 2); // 8.39 MB
    _Float16* vbuf  = (_Float16*)alloc((size_t)16 * 1024 * 1024 * 2);   // 33.55 MB
    _Float16* xxT_l = (_Float16*)alloc((size_t)16 * 1024 * 1024 * 2);   // 33.55 MB

    prep<<<dim3(6, 16, 17), dim3(256), 0, stream>>>(
        x, wq, wk, wv, wp, bnq, bnk, bnv, bnp,
        xT_hi, xT_lo, wqk_h, wqk_l, wv_h, wp_h, s_qkv, t_qkv, s_p, t_p);

    gemm_qkv<<<dim3(12, 8, 16), dim3(256), 0, stream>>>(
        wqk_h, wqk_l, wv_h, xT_hi, xT_lo, s_qkv, t_qkv,
        qT_h, qT_l, kT_h, kT_l, vbuf);

    attn<<<dim3(128, 8), dim3(256), 0, stream>>>(qT_h, qT_l, kT_h, kT_l, vbuf, xxT_h, xxT_l);

    gemm_out<<<dim3(3, 16, 16), dim3(256), 0, stream>>>(wp_h, xxT_h, s_p, t_p, out);
}